// Round 7
// baseline (1926.770 us; speedup 1.0000x reference)
//
#include <hip/hip_runtime.h>
#include <hip/hip_bf16.h>
#include <cstdint>
#include <cstddef>

typedef float  f32x4  __attribute__((ext_vector_type(4)));
typedef __bf16 bf16x8 __attribute__((ext_vector_type(8)));

#define DEV __device__ __forceinline__

DEV float gelu_f(float x){ return 0.5f * x * (1.0f + erff(x * 0.70710678118654752f)); }

// async global->LDS, 16B/lane; LDS dest = wave-uniform base + lane*16
DEV void gl16(void* lds, const void* g){
  __builtin_amdgcn_global_load_lds((const __attribute__((address_space(1))) void*)g,
                                   (__attribute__((address_space(3))) void*)lds, 16, 0, 0);
}

// ---------------- workspace layout (bytes) ----------------
static constexpr size_t OFF_FX     = 0;                       // fx fp32 [16384,512]     33554432
static constexpr size_t OFF_H      = 33554432;                // h bf16 [16384,512]      16777216
static constexpr size_t OFF_REGA   = 50331648;                // 67108864 region
static constexpr size_t OFF_COMB   = OFF_REGA;                // fp32 [16384,768] (fx_mid 0-511; 512-767 unused now)
static constexpr size_t OFF_SW     = OFF_REGA + 50331648;     // fp32 [16,8192,32]       16777216
static constexpr size_t OFF_MLPH   = OFF_REGA;                // bf16 [16384,2048] (after comb/sw dead)
static constexpr size_t OFF_H1     = OFF_REGA;                // bf16 [16384,1024] (preprocess only)
static constexpr size_t OFF_OUTB   = OFF_REGA + 67108864;     // bf16 [16384,512]        16777216
static constexpr size_t OFF_PT     = OFF_OUTB + 16777216;     // fp32 [16,16,32,64]      2097152
static constexpr size_t OFF_PTM    = OFF_PT + 2097152;        // fp32 [16,16,32]         32768
static constexpr size_t OFF_OT     = OFF_PTM + 32768;         // fp32 [16,32,64]         131072
static constexpr size_t OFF_WT     = OFF_OT + 131072;         // bf16 weights (22 MB)
static constexpr size_t OFF_BIAS   = OFF_WT + 23068672;       // bcat[4][768] f32, then bpre2p[512] f32

// ---------------- weight prep ----------------
__global__ __launch_bounds__(256) void wtrans_k(const float* __restrict__ W, __bf16* __restrict__ Wt,
                                                int K, int N, size_t wstride, size_t wtstride)
{
  __shared__ float tile[64][65];
  W  += (size_t)blockIdx.z * wstride;
  Wt += (size_t)blockIdx.z * wtstride;
  int t = threadIdx.x;
  int k0 = blockIdx.x * 64, n0 = blockIdx.y * 64;
  #pragma unroll
  for (int i = 0; i < 16; i++){
    int e = t + 256*i; int kk = e >> 6, nn = e & 63;
    tile[kk][nn] = W[(size_t)(k0+kk)*N + n0+nn];
  }
  __syncthreads();
  #pragma unroll
  for (int i = 0; i < 16; i++){
    int e = t + 256*i; int nn = e >> 6, kk = e & 63;
    Wt[(size_t)(n0+nn)*K + k0+kk] = (__bf16)tile[kk][nn];
  }
}

// Wxst -> rows 512+hg of Btcat[l]; blog -> bcat[l][512+hg]
__global__ __launch_bounds__(128) void prep_wxs_k(const float* __restrict__ Wx, const float* __restrict__ Wsl,
                                                  const float* __restrict__ bx, const float* __restrict__ bsl,
                                                  const float* __restrict__ temp,
                                                  __bf16* __restrict__ Btcat, float* __restrict__ bcat)
{
  __shared__ float wsc[64];
  int l = blockIdx.y;
  const float* Wx_l  = Wx  + (size_t)l*262144;
  const float* Wsl_l = Wsl + l*2048;
  const float* bx_l  = bx  + l*512;
  const float* bsl_l = bsl + l*32;
  __bf16* Wt_l = Btcat + (size_t)l*393216 + (size_t)512*512;
  float* blog_l = bcat + l*768 + 512;
  int hg = blockIdx.x; int h = hg >> 5, g = hg & 31;
  int t = threadIdx.x;
  if (t < 64) wsc[t] = Wsl_l[t*32 + g];
  __syncthreads();
  float invt = 1.0f / temp[l*8 + h];
  #pragma unroll
  for (int cc = 0; cc < 4; cc++){
    int c = t + cc*128;
    float a = 0.f;
    for (int d = 0; d < 64; d++) a += Wx_l[(size_t)c*512 + h*64 + d] * wsc[d];
    Wt_l[(size_t)hg*512 + c] = (__bf16)(a * invt);
  }
  if (t == 0){
    float a = 0.f;
    for (int d = 0; d < 64; d++) a += bx_l[h*64 + d] * wsc[d];
    blog_l[hg] = (a + bsl_l[g]) * invt;
  }
}

__global__ __launch_bounds__(256) void bias_setup_k(const float* __restrict__ b_pre2, const float* __restrict__ placeholder,
                                                    const float* __restrict__ bfx,
                                                    float* __restrict__ bpre2p, float* __restrict__ bcat)
{
  int i = blockIdx.x*256 + threadIdx.x;   // 0..2559
  if (i < 512) bpre2p[i] = b_pre2[i] + placeholder[i];
  else if (i < 2560){
    int j = i - 512; int l = j >> 9, c = j & 511;
    bcat[l*768 + c] = bfx[l*512 + c];
  }
}

// ---------------- preprocess stage 1 ----------------
__global__ __launch_bounds__(256) void preproc1_k(const float* __restrict__ fun, const float* __restrict__ emb,
                                                  const float* __restrict__ W1, const float* __restrict__ b1,
                                                  __bf16* __restrict__ h1)
{
  __shared__ float w1l[10][1024];
  int t = threadIdx.x;
  for (int i = t*4; i < 10240; i += 1024) *(f32x4*)&w1l[0][i] = *(const f32x4*)&W1[i];
  __syncthreads();
  f32x4 bv = *(const f32x4*)&b1[t*4];
  int r0 = blockIdx.x * 4;
  for (int r = 0; r < 4; r++){
    int m = r0 + r;
    const float* er = emb + (size_t)m*3;
    const float* fr = fun + (size_t)m*7;
    float x[10];
    x[0]=er[0]; x[1]=er[1]; x[2]=er[2];
    #pragma unroll
    for (int c = 0; c < 7; c++) x[3+c] = fr[c];
    f32x4 acc = bv;
    #pragma unroll
    for (int c = 0; c < 10; c++){
      f32x4 wv = *(const f32x4*)&w1l[c][t*4];
      acc += x[c] * wv;
    }
    __bf16* op = h1 + (size_t)m*1024 + t*4;
    #pragma unroll
    for (int e = 0; e < 4; e++) op[e] = (__bf16)gelu_f(acc[e]);
  }
}

// ---------------- wide-tile MFMA GEMM: 256xBN block (512 thr, 8 waves), ping/pong gl_lds ----------------
// R7: 2 LDS buffers (64KB @ BN=256) -> 2 blocks/CU co-resident on big-grid GEMMs, so one
// block's MFMA covers the other's vmcnt/barrier stalls (m114 overlap).
// EPI: 0 = fp32 +bias | 1 = bf16 gelu | 2 = fp32 +bias+res | 4 = comb: y<2 like 0, y==2 fused
// slice-softmax written straight to sw (outp2), killing the softmax_k pass.
template<int EPI, int BN>
__global__ __launch_bounds__(512) void gemm_wide(const __bf16* __restrict__ A, const __bf16* __restrict__ Bt,
                                                 const float* __restrict__ bias, const float* __restrict__ res,
                                                 void* __restrict__ outp, void* __restrict__ outp2,
                                                 int N, int lgK)
{
  constexpr int NSUB_B = BN/16;
  constexpr int S = 16 + NSUB_B;           // 32 (BN=256) or 24 (BN=128) subtiles per stage
  constexpr int Q = S/8;                   // gl16 per wave per stage: 4 or 3
  constexpr int NJ = BN/32;                // n-frags per wave: 8 or 4
  __shared__ bf16x8 ldsAB[2][S][64];       // [buf][subtile][lane]
  const int tid = threadIdx.x;
  const int w = tid >> 6, lane = tid & 63;
  const int lm = lane & 15, lq = lane >> 4;
  const int wr = w >> 1, wc = w & 1;       // wave grid 4x2; wave tile 64 x (BN/2)
  const int m0 = blockIdx.x * 256, n0 = blockIdx.y * BN;
  const int niter = 1 << (lgK - 5);

  auto issue = [&](int i){
    unsigned buf = (unsigned)i & 1u;
    int kk = i << 5;
    #pragma unroll
    for (int q = 0; q < Q; q++){
      int f = w*Q + q;                     // flat subtile index (wave-uniform)
      const __bf16* p = (f < 16)
        ? A  + (((size_t)(m0 + f*16 + lm)) << lgK) + kk + lq*8
        : Bt + (((size_t)(n0 + (f-16)*16 + lm)) << lgK) + kk + lq*8;
      gl16(&ldsAB[buf][f][0], p);
    }
  };

  issue(0);

  f32x4 acc[4][NJ] = {};

  for (int i = 0; i < niter; ++i){
    if (i + 1 < niter){
      issue(i + 1);
      if constexpr (Q == 4) __builtin_amdgcn_s_waitcnt(0x0F74);  // vmcnt(4)
      else                  __builtin_amdgcn_s_waitcnt(0x0F73);  // vmcnt(3)
    } else {
      __builtin_amdgcn_s_waitcnt(0x0F70);                        // vmcnt(0)
    }
    __builtin_amdgcn_s_barrier();          // stage i resident for all waves
    const unsigned buf = (unsigned)i & 1u;
    bf16x8 af[4], bfr[NJ];
    #pragma unroll
    for (int ii = 0; ii < 4; ii++)  af[ii]  = ldsAB[buf][wr*4 + ii][lane];
    #pragma unroll
    for (int jj = 0; jj < NJ; jj++) bfr[jj] = ldsAB[buf][16 + wc*NJ + jj][lane];
    #pragma unroll
    for (int ii = 0; ii < 4; ii++)
      #pragma unroll
      for (int jj = 0; jj < NJ; jj++)
        acc[ii][jj] = __builtin_amdgcn_mfma_f32_16x16x32_bf16(af[ii], bfr[jj], acc[ii][jj], 0, 0, 0);
    __builtin_amdgcn_s_barrier();          // stage i consumed before its buffer is re-targeted
  }

  if (EPI == 4 && blockIdx.y == 2){
    // fused slice-softmax: this block's cols are all 256 logits (head h = c2>>5, g = c2&31).
    // One (row,head)'s 32 logits live in 2 jj-frags x 16 lm lanes (same lq) -> shfl reduce.
    float* swp = (float*)outp2;
    #pragma unroll
    for (int ii = 0; ii < 4; ii++){
      int row0 = m0 + wr*64 + ii*16 + lq*4;
      #pragma unroll
      for (int hp = 0; hp < 4; hp++){
        int j0 = hp*2, j1 = j0 + 1;
        int h = wc*4 + hp;
        float b0 = bias[512 + wc*128 + j0*16 + lm];
        float b1 = bias[512 + wc*128 + j1*16 + lm];
        #pragma unroll
        for (int r = 0; r < 4; r++){
          int row = row0 + r;
          float v0 = acc[ii][j0][r] + b0;
          float v1 = acc[ii][j1][r] + b1;
          float mx = fmaxf(v0, v1);
          #pragma unroll
          for (int msk = 8; msk; msk >>= 1) mx = fmaxf(mx, __shfl_xor(mx, msk));
          float e0 = expf(v0 - mx), e1 = expf(v1 - mx);
          float ss = e0 + e1;
          #pragma unroll
          for (int msk = 8; msk; msk >>= 1) ss += __shfl_xor(ss, msk);
          float inv = 1.f / ss;
          int b = row >> 13, n = row & 8191;
          float* op = swp + ((size_t)(b*8 + h)*8192 + n)*32;
          op[lm]      = e0 * inv;
          op[16 + lm] = e1 * inv;
        }
      }
    }
    return;
  }

  #pragma unroll
  for (int ii = 0; ii < 4; ii++){
    int row0 = m0 + wr*64 + ii*16 + lq*4;
    #pragma unroll
    for (int jj = 0; jj < NJ; jj++){
      int col = n0 + wc*(BN/2) + jj*16 + lm;
      float bv = bias[col];
      #pragma unroll
      for (int r = 0; r < 4; r++){
        size_t idx = (size_t)(row0 + r)*N + col;
        float v = acc[ii][jj][r] + bv;
        if (EPI == 2) v += res[idx];
        if (EPI == 1) ((__bf16*)outp)[idx] = (__bf16)gelu_f(v);
        else          ((float*)outp)[idx]  = v;
      }
    }
  }
}

// ---------------- LayerNorm (512 cols), fp32 in -> bf16 out; 1 wave/row ----------------
__global__ __launch_bounds__(256) void ln_k(const float* __restrict__ x, const float* __restrict__ g,
                                            const float* __restrict__ b, __bf16* __restrict__ out)
{
  int w = threadIdx.x >> 6, lane = threadIdx.x & 63;
  int row = blockIdx.x*4 + w;
  const float* xr = x + (size_t)row*512 + lane*8;
  float v[8];
  *(f32x4*)&v[0] = *(const f32x4*)xr;
  *(f32x4*)&v[4] = *(const f32x4*)(xr + 4);
  float s = 0.f, sq = 0.f;
  #pragma unroll
  for (int e = 0; e < 8; e++){ s += v[e]; sq += v[e]*v[e]; }
  #pragma unroll
  for (int off = 32; off; off >>= 1){ s += __shfl_xor(s, off); sq += __shfl_xor(sq, off); }
  float mean = s * (1.f/512.f);
  float var  = sq * (1.f/512.f) - mean*mean;
  float rstd = rsqrtf(var + 1e-5f);
  float gv[8], bv[8];
  *(f32x4*)&gv[0] = *(const f32x4*)(g + lane*8);
  *(f32x4*)&gv[4] = *(const f32x4*)(g + lane*8 + 4);
  *(f32x4*)&bv[0] = *(const f32x4*)(b + lane*8);
  *(f32x4*)&bv[4] = *(const f32x4*)(b + lane*8 + 4);
  __bf16* op = out + (size_t)row*512 + lane*8;
  #pragma unroll
  for (int e = 0; e < 8; e++) op[e] = (__bf16)((v[e]-mean)*rstd*gv[e] + bv[e]);
}

// ---------------- token partial: per (chunk, bh) accumulate sw^T @ fx_mid over 512 n ----------------
__global__ __launch_bounds__(256) void token_part_k(const float* __restrict__ comb, const float* __restrict__ sw,
                                                    float* __restrict__ pt, float* __restrict__ ptm)
{
  __shared__ float fxl[32][64];
  __shared__ float swl[32][32];
  int t = threadIdx.x;
  int chunk = blockIdx.x, bh = blockIdx.y;
  int b = bh >> 3, h = bh & 7;
  int d = t & 63, gg = (t >> 6) * 8;
  float acc[8] = {0,0,0,0,0,0,0,0};
  float macc = 0.f;
  for (int s = 0; s < 16; s++){
    int nbase = chunk*512 + s*32;
    __syncthreads();
    #pragma unroll
    for (int i = 0; i < 2; i++){
      int e = t + 256*i; int rv = e >> 4, c4 = e & 15;
      *(f32x4*)&fxl[rv][c4*4] = *(const f32x4*)&comb[((size_t)b*8192 + nbase + rv)*768 + h*64 + c4*4];
    }
    { int rv = t >> 3, c4 = t & 7;
      *(f32x4*)&swl[rv][c4*4] = *(const f32x4*)&sw[((size_t)bh*8192 + nbase + rv)*32 + c4*4]; }
    __syncthreads();
    for (int nn = 0; nn < 32; nn++){
      float f = fxl[nn][d];
      #pragma unroll
      for (int jj = 0; jj < 8; jj++) acc[jj] += f * swl[nn][gg+jj];
    }
    if (t < 32){ for (int nn = 0; nn < 32; nn++) macc += swl[nn][t]; }
  }
  int cb = chunk*16 + bh;
  #pragma unroll
  for (int jj = 0; jj < 8; jj++)
    pt[((size_t)cb*32 + gg + jj)*64 + d] = acc[jj];
  if (t < 32) ptm[cb*32 + t] = macc;
}

// ---------------- token reduce + tiny attention per (b,h), fused ----------------
__global__ __launch_bounds__(256) void attn_k(const float* __restrict__ pt, const float* __restrict__ ptm,
                                              const float* __restrict__ Wq, const float* __restrict__ Wk,
                                              const float* __restrict__ Wv, float* __restrict__ ot)
{
  __shared__ float tok[32][64];
  __shared__ float ml[32];
  __shared__ float qq[32][65], kk2[32][65], vv[32][65];
  __shared__ float at[32][33];
  int t = threadIdx.x, bh = blockIdx.x;
  if (t < 32){
    float s = 0.f;
    for (int c = 0; c < 16; c++) s += ptm[(c*16 + bh)*32 + t];
    ml[t] = s + 1e-5f;
  }
  __syncthreads();
  #pragma unroll
  for (int i = 0; i < 8; i++){
    int e = t + 256*i; int g = e >> 6, d = e & 63;
    float s = 0.f;
    for (int c = 0; c < 16; c++) s += pt[((size_t)(c*16 + bh)*32 + g)*64 + d];
    tok[g][d] = s / ml[g];
  }
  __syncthreads();
  #pragma unroll
  for (int i = 0; i < 8; i++){
    int e = t + 256*i; int g = e >> 6, j = e & 63;
    float aq = 0.f, ak = 0.f, av = 0.f;
    for (int d = 0; d < 64; d++){
      float tv = tok[g][d];
      aq += tv * Wq[d*64 + j];
      ak += tv * Wk[d*64 + j];
      av += tv * Wv[d*64 + j];
    }
    qq[g][j] = aq; kk2[g][j] = ak; vv[g][j] = av;
  }
  __syncthreads();
  #pragma unroll
  for (int i = 0; i < 4; i++){
    int e = t + 256*i; int g = e >> 5, j2 = e & 31;
    float s2 = 0.f;
    for (int d = 0; d < 64; d++) s2 += qq[g][d] * kk2[j2][d];
    at[g][j2] = s2 * 0.125f;
  }
  __syncthreads();
  if (t < 32){
    float mx = at[t][0];
    for (int j = 1; j < 32; j++) mx = fmaxf(mx, at[t][j]);
    float ss = 0.f;
    for (int j = 0; j < 32; j++){ float e2 = expf(at[t][j]-mx); at[t][j] = e2; ss += e2; }
    float inv = 1.f / ss;
    for (int j = 0; j < 32; j++) at[t][j] *= inv;
  }
  __syncthreads();
  #pragma unroll
  for (int i = 0; i < 8; i++){
    int e = t + 256*i; int g = e >> 6, d = e & 63;
    float s3 = 0.f;
    for (int j = 0; j < 32; j++) s3 += at[g][j] * vv[j][d];
    ot[(size_t)bh*2048 + e] = s3;
  }
}

// ---------------- de-slice ----------------
__global__ __launch_bounds__(256) void deslice_k(const float* __restrict__ ot, const float* __restrict__ sw,
                                                 __bf16* __restrict__ outb)
{
  __shared__ float otl[32][64];
  __shared__ float swl[4][33];
  int t = threadIdx.x;
  int chunk = blockIdx.x, bh = blockIdx.y;
  int b = bh >> 3, h = bh & 7;
  #pragma unroll
  for (int i = 0; i < 8; i++){
    int e = t + 256*i;
    otl[e>>6][e&63] = ot[(size_t)bh*2048 + e];
  }
  int n0 = chunk*128;
  int nsub = t >> 6, d = t & 63;
  for (int s = 0; s < 32; s++){
    __syncthreads();
    if (t < 128) swl[t>>5][t&31] = sw[((size_t)bh*8192 + n0 + s*4 + (t>>5))*32 + (t&31)];
    __syncthreads();
    float a2 = 0.f;
    #pragma unroll
    for (int g = 0; g < 32; g++) a2 += otl[g][d] * swl[nsub][g];
    int n = n0 + s*4 + nsub;
    outb[((size_t)(b*8192 + n))*512 + h*64 + d] = (__bf16)a2;
  }
}

// ---------------- final head ----------------
__global__ __launch_bounds__(256) void head_k(const float* __restrict__ x, const float* __restrict__ g,
                                              const float* __restrict__ b, const float* __restrict__ Wout,
                                              const float* __restrict__ bout, float* __restrict__ out)
{
  int w = threadIdx.x >> 6, lane = threadIdx.x & 63;
  int row = blockIdx.x*4 + w;
  const float* xr = x + (size_t)row*512 + lane*8;
  float v[8];
  *(f32x4*)&v[0] = *(const f32x4*)xr;
  *(f32x4*)&v[4] = *(const f32x4*)(xr + 4);
  float s = 0.f, sq = 0.f;
  #pragma unroll
  for (int e = 0; e < 8; e++){ s += v[e]; sq += v[e]*v[e]; }
  #pragma unroll
  for (int off = 32; off; off >>= 1){ s += __shfl_xor(s, off); sq += __shfl_xor(sq, off); }
  float mean = s * (1.f/512.f);
  float rstd = rsqrtf(sq * (1.f/512.f) - mean*mean + 1e-5f);
  float o[4] = {0,0,0,0};
  #pragma unroll
  for (int e = 0; e < 8; e++){
    int c = lane*8 + e;
    float yn = (v[e]-mean)*rstd*g[c] + b[c];
    const float* wr = Wout + (size_t)c*4;
    o[0] += yn*wr[0]; o[1] += yn*wr[1]; o[2] += yn*wr[2]; o[3] += yn*wr[3];
  }
  #pragma unroll
  for (int off = 32; off; off >>= 1){
    #pragma unroll
    for (int j = 0; j < 4; j++) o[j] += __shfl_xor(o[j], off);
  }
  if (lane == 0){
    #pragma unroll
    for (int j = 0; j < 4; j++) out[(size_t)row*4 + j] = o[j] + bout[j];
  }
}

extern "C" void kernel_launch(void* const* d_in, const int* in_sizes, int n_in,
                              void* d_out, int out_size, void* d_ws, size_t ws_size,
                              hipStream_t stream)
{
  const float* fun    = (const float*)d_in[0];
  const float* emb    = (const float*)d_in[1];
  const float* W_pre1 = (const float*)d_in[2];
  const float* b_pre1 = (const float*)d_in[3];
  const float* W_pre2 = (const float*)d_in[4];
  const float* b_pre2 = (const float*)d_in[5];
  const float* placeholder = (const float*)d_in[6];
  const float* ln1_g  = (const float*)d_in[7];
  const float* ln1_b  = (const float*)d_in[8];
  const float* Wfx    = (const float*)d_in[9];
  const float* bfx    = (const float*)d_in[10];
  const float* Wx     = (const float*)d_in[11];
  const float* bx     = (const float*)d_in[12];
  const float* Wslice = (const float*)d_in[13];
  const float* bslice = (const float*)d_in[14];
  const float* temp   = (const float*)d_in[15];
  const float* Wq     = (const float*)d_in[16];
  const float* Wk     = (const float*)d_in[17];
  const float* Wv     = (const float*)d_in[18];
  const float* Wo     = (const float*)d_in[19];
  const float* bo     = (const float*)d_in[20];
  const float* ln2_g  = (const float*)d_in[21];
  const float* ln2_b  = (const float*)d_in[22];
  const float* Wm1    = (const float*)d_in[23];
  const float* bm1    = (const float*)d_in[24];
  const float* Wm2    = (const float*)d_in[25];
  const float* bm2    = (const float*)d_in[26];
  const float* lnf_g  = (const float*)d_in[27];
  const float* lnf_b  = (const float*)d_in[28];
  const float* Wout   = (const float*)d_in[29];
  const float* bout   = (const float*)d_in[30];

  char* ws = (char*)d_ws;
  float*  fx     = (float*)(ws + OFF_FX);
  __bf16* hbf    = (__bf16*)(ws + OFF_H);
  float*  comb   = (float*)(ws + OFF_COMB);
  float*  sw     = (float*)(ws + OFF_SW);
  __bf16* mlph   = (__bf16*)(ws + OFF_MLPH);
  __bf16* h1bf   = (__bf16*)(ws + OFF_H1);
  __bf16* outb   = (__bf16*)(ws + OFF_OUTB);
  float*  pt     = (float*)(ws + OFF_PT);
  float*  ptm    = (float*)(ws + OFF_PTM);
  float*  ot     = (float*)(ws + OFF_OT);
  __bf16* Wpre2t = (__bf16*)(ws + OFF_WT);
  __bf16* Btcat  = (__bf16*)(ws + OFF_WT + 1048576);
  __bf16* Wot    = (__bf16*)(ws + OFF_WT + 4194304);
  __bf16* Wm1t   = (__bf16*)(ws + OFF_WT + 6291456);
  __bf16* Wm2t   = (__bf16*)(ws + OFF_WT + 14680064);
  float*  bcat   = (float*)(ws + OFF_BIAS);
  float*  bpre2p = (float*)(ws + OFF_BIAS + 4*768*4);

  // ---- weight prep ----
  wtrans_k<<<dim3(16,8,1), 256,0,stream>>>(W_pre2, Wpre2t, 1024, 512, 0, 0);
  wtrans_k<<<dim3(8,8,4),  256,0,stream>>>(Wfx, Btcat, 512, 512, 262144, 393216);  // rows 0-511 of each cat
  wtrans_k<<<dim3(8,8,4),  256,0,stream>>>(Wo,  Wot,  512, 512, 262144, 262144);
  wtrans_k<<<dim3(8,32,4), 256,0,stream>>>(Wm1, Wm1t, 512, 2048, 1048576, 1048576);
  wtrans_k<<<dim3(32,8,4), 256,0,stream>>>(Wm2, Wm2t, 2048, 512, 1048576, 1048576);
  prep_wxs_k<<<dim3(256,4),128,0,stream>>>(Wx, Wslice, bx, bslice, temp, Btcat, bcat);
  bias_setup_k<<<10,256,0,stream>>>(b_pre2, placeholder, bfx, bpre2p, bcat);

  // ---- preprocess ----
  preproc1_k<<<4096,256,0,stream>>>(fun, emb, W_pre1, b_pre1, h1bf);
  // M=16384, N=512, K=1024 -> 256x128 tiles, grid 64x4
  gemm_wide<0,128><<<dim3(64,4),512,0,stream>>>(h1bf, Wpre2t, bpre2p, nullptr, (void*)fx, nullptr, 512, 10);

  // ---- layers ----
  for (int l = 0; l < 4; l++){
    ln_k<<<4096,256,0,stream>>>(fx, ln1_g + l*512, ln1_b + l*512, hbf);
    // N=768, K=512 -> 256x256 tiles, grid 64x3; y==2 block emits sw via fused softmax
    gemm_wide<4,256><<<dim3(64,3),512,0,stream>>>(hbf, Btcat + (size_t)l*393216, bcat + l*768, nullptr, (void*)comb, (void*)sw, 768, 9);
    token_part_k<<<dim3(16,16),256,0,stream>>>(comb, sw, pt, ptm);
    attn_k<<<16,256,0,stream>>>(pt, ptm, Wq + l*4096, Wk + l*4096, Wv + l*4096, ot);
    deslice_k<<<dim3(64,16),256,0,stream>>>(ot, sw, outb);
    // N=512, K=512 -> 256x128 tiles, grid 64x4
    gemm_wide<2,128><<<dim3(64,4),512,0,stream>>>(outb, Wot + (size_t)l*262144, bo + l*512, fx, (void*)fx, nullptr, 512, 9);
    ln_k<<<4096,256,0,stream>>>(fx, ln2_g + l*512, ln2_b + l*512, hbf);
    // N=2048, K=512 -> 256x256 tiles, grid 64x8 (512 blocks -> 2/CU with 64KB LDS)
    gemm_wide<1,256><<<dim3(64,8),512,0,stream>>>(hbf, Wm1t + (size_t)l*1048576, bm1 + l*2048, nullptr, (void*)mlph, nullptr, 2048, 9);
    // N=512, K=2048 -> 256x128 tiles, grid 64x4
    gemm_wide<2,128><<<dim3(64,4),512,0,stream>>>(mlph, Wm2t + (size_t)l*1048576, bm2 + l*512, fx, (void*)fx, nullptr, 512, 11);
  }

  // ---- head ----
  head_k<<<4096,256,0,stream>>>(fx, lnf_g, lnf_b, Wout, bout, (float*)d_out);
}

// Round 8
// 1446.667 us; speedup vs baseline: 1.3319x; 1.3319x over previous
//
#include <hip/hip_runtime.h>
#include <hip/hip_bf16.h>
#include <cstdint>
#include <cstddef>

typedef float  f32x4  __attribute__((ext_vector_type(4)));
typedef __bf16 bf16x8 __attribute__((ext_vector_type(8)));

#define DEV __device__ __forceinline__

DEV float gelu_f(float x){ return 0.5f * x * (1.0f + erff(x * 0.70710678118654752f)); }

// async global->LDS, 16B/lane; LDS dest = wave-uniform base + lane*16
DEV void gl16(void* lds, const void* g){
  __builtin_amdgcn_global_load_lds((const __attribute__((address_space(1))) void*)g,
                                   (__attribute__((address_space(3))) void*)lds, 16, 0, 0);
}

// ---------------- workspace layout (bytes) ----------------
static constexpr size_t OFF_FX     = 0;                       // fx fp32 [16384,512]     33554432
static constexpr size_t OFF_H      = 33554432;                // h bf16 [16384,512]      16777216
static constexpr size_t OFF_REGA   = 50331648;                // 67108864 region
static constexpr size_t OFF_COMB   = OFF_REGA;                // fp32 [16384,768] (fx_mid 0-511)
static constexpr size_t OFF_SW     = OFF_REGA + 50331648;     // fp32 [16,8192,32]       16777216
static constexpr size_t OFF_MLPH   = OFF_REGA;                // bf16 [16384,2048] (after comb/sw dead)
static constexpr size_t OFF_H1     = OFF_REGA;                // bf16 [16384,1024] (preprocess only)
static constexpr size_t OFF_OUTB   = OFF_REGA + 67108864;     // bf16 [16384,512]        16777216
static constexpr size_t OFF_PT     = OFF_OUTB + 16777216;     // fp32 [16,16,32,64]      2097152
static constexpr size_t OFF_PTM    = OFF_PT + 2097152;        // fp32 [16,16,32]         32768
static constexpr size_t OFF_OT     = OFF_PTM + 32768;         // fp32 [16,32,64]         131072
static constexpr size_t OFF_WT     = OFF_OT + 131072;         // bf16 weights (22 MB)
static constexpr size_t OFF_BIAS   = OFF_WT + 23068672;       // bcat[4][768] f32, then bpre2p[512] f32

// ---------------- weight prep ----------------
__global__ __launch_bounds__(256) void wtrans_k(const float* __restrict__ W, __bf16* __restrict__ Wt,
                                                int K, int N, size_t wstride, size_t wtstride)
{
  __shared__ float tile[64][65];
  W  += (size_t)blockIdx.z * wstride;
  Wt += (size_t)blockIdx.z * wtstride;
  int t = threadIdx.x;
  int k0 = blockIdx.x * 64, n0 = blockIdx.y * 64;
  #pragma unroll
  for (int i = 0; i < 16; i++){
    int e = t + 256*i; int kk = e >> 6, nn = e & 63;
    tile[kk][nn] = W[(size_t)(k0+kk)*N + n0+nn];
  }
  __syncthreads();
  #pragma unroll
  for (int i = 0; i < 16; i++){
    int e = t + 256*i; int nn = e >> 6, kk = e & 63;
    Wt[(size_t)(n0+nn)*K + k0+kk] = (__bf16)tile[kk][nn];
  }
}

// Wxst -> rows 512+hg of Btcat[l]; blog -> bcat[l][512+hg]
__global__ __launch_bounds__(128) void prep_wxs_k(const float* __restrict__ Wx, const float* __restrict__ Wsl,
                                                  const float* __restrict__ bx, const float* __restrict__ bsl,
                                                  const float* __restrict__ temp,
                                                  __bf16* __restrict__ Btcat, float* __restrict__ bcat)
{
  __shared__ float wsc[64];
  int l = blockIdx.y;
  const float* Wx_l  = Wx  + (size_t)l*262144;
  const float* Wsl_l = Wsl + l*2048;
  const float* bx_l  = bx  + l*512;
  const float* bsl_l = bsl + l*32;
  __bf16* Wt_l = Btcat + (size_t)l*393216 + (size_t)512*512;
  float* blog_l = bcat + l*768 + 512;
  int hg = blockIdx.x; int h = hg >> 5, g = hg & 31;
  int t = threadIdx.x;
  if (t < 64) wsc[t] = Wsl_l[t*32 + g];
  __syncthreads();
  float invt = 1.0f / temp[l*8 + h];
  #pragma unroll
  for (int cc = 0; cc < 4; cc++){
    int c = t + cc*128;
    float a = 0.f;
    for (int d = 0; d < 64; d++) a += Wx_l[(size_t)c*512 + h*64 + d] * wsc[d];
    Wt_l[(size_t)hg*512 + c] = (__bf16)(a * invt);
  }
  if (t == 0){
    float a = 0.f;
    for (int d = 0; d < 64; d++) a += bx_l[h*64 + d] * wsc[d];
    blog_l[hg] = (a + bsl_l[g]) * invt;
  }
}

__global__ __launch_bounds__(256) void bias_setup_k(const float* __restrict__ b_pre2, const float* __restrict__ placeholder,
                                                    const float* __restrict__ bfx,
                                                    float* __restrict__ bpre2p, float* __restrict__ bcat)
{
  int i = blockIdx.x*256 + threadIdx.x;   // 0..2559
  if (i < 512) bpre2p[i] = b_pre2[i] + placeholder[i];
  else if (i < 2560){
    int j = i - 512; int l = j >> 9, c = j & 511;
    bcat[l*768 + c] = bfx[l*512 + c];
  }
}

// ---------------- preprocess stage 1 ----------------
__global__ __launch_bounds__(256) void preproc1_k(const float* __restrict__ fun, const float* __restrict__ emb,
                                                  const float* __restrict__ W1, const float* __restrict__ b1,
                                                  __bf16* __restrict__ h1)
{
  __shared__ float w1l[10][1024];
  int t = threadIdx.x;
  for (int i = t*4; i < 10240; i += 1024) *(f32x4*)&w1l[0][i] = *(const f32x4*)&W1[i];
  __syncthreads();
  f32x4 bv = *(const f32x4*)&b1[t*4];
  int r0 = blockIdx.x * 4;
  for (int r = 0; r < 4; r++){
    int m = r0 + r;
    const float* er = emb + (size_t)m*3;
    const float* fr = fun + (size_t)m*7;
    float x[10];
    x[0]=er[0]; x[1]=er[1]; x[2]=er[2];
    #pragma unroll
    for (int c = 0; c < 7; c++) x[3+c] = fr[c];
    f32x4 acc = bv;
    #pragma unroll
    for (int c = 0; c < 10; c++){
      f32x4 wv = *(const f32x4*)&w1l[c][t*4];
      acc += x[c] * wv;
    }
    __bf16* op = h1 + (size_t)m*1024 + t*4;
    #pragma unroll
    for (int e = 0; e < 4; e++) op[e] = (__bf16)gelu_f(acc[e]);
  }
}

// ---------------- wide-tile MFMA GEMM: 256xBN block (512 thr, 8 waves), depth-3 gl_lds (4 bufs) ----------------
// R8: delivery rate tracks outstanding gl_lds requests (R5 vs R6 vs R7 evidence). Depth-3 keeps
// 12 loads/wave (~96/CU) in flight at the 256-wide tile's halved bytes/FLOP.
// EPI: 0 = fp32 +bias | 1 = bf16 gelu | 2 = fp32 +bias+res | 4 = comb: y<2 like 0, y==2 fused
// slice-softmax straight to sw (outp2).
template<int EPI, int BN>
__global__ __launch_bounds__(512) void gemm_wide(const __bf16* __restrict__ A, const __bf16* __restrict__ Bt,
                                                 const float* __restrict__ bias, const float* __restrict__ res,
                                                 void* __restrict__ outp, void* __restrict__ outp2,
                                                 int N, int lgK)
{
  constexpr int NSUB_B = BN/16;
  constexpr int S = 16 + NSUB_B;           // 32 (BN=256) or 24 (BN=128) subtiles per stage
  constexpr int Q = S/8;                   // gl16 per wave per stage: 4 or 3
  constexpr int NJ = BN/32;                // n-frags per wave: 8 or 4
  __shared__ bf16x8 ldsAB[4][S][64];       // [buf][subtile][lane]; 128KB / 96KB
  const int tid = threadIdx.x;
  const int w = tid >> 6, lane = tid & 63;
  const int lm = lane & 15, lq = lane >> 4;
  const int wr = w >> 1, wc = w & 1;       // wave grid 4x2; wave tile 64 x (BN/2)
  const int m0 = blockIdx.x * 256, n0 = blockIdx.y * BN;
  const int niter = 1 << (lgK - 5);

  auto issue = [&](int i){
    unsigned buf = (unsigned)i & 3u;
    int kk = i << 5;
    #pragma unroll
    for (int q = 0; q < Q; q++){
      int f = w*Q + q;                     // flat subtile index (wave-uniform)
      const __bf16* p = (f < 16)
        ? A  + (((size_t)(m0 + f*16 + lm)) << lgK) + kk + lq*8
        : Bt + (((size_t)(n0 + (f-16)*16 + lm)) << lgK) + kk + lq*8;
      gl16(&ldsAB[buf][f][0], p);
    }
  };

  issue(0); issue(1); issue(2);

  f32x4 acc[4][NJ] = {};

  for (int i = 0; i < niter; ++i){
    if (i + 3 < niter){
      issue(i + 3);
      if constexpr (Q == 4) __builtin_amdgcn_s_waitcnt(0x0F7C);  // vmcnt(12)
      else                  __builtin_amdgcn_s_waitcnt(0x0F79);  // vmcnt(9)
    } else if (i + 2 < niter){
      if constexpr (Q == 4) __builtin_amdgcn_s_waitcnt(0x0F78);  // vmcnt(8)
      else                  __builtin_amdgcn_s_waitcnt(0x0F76);  // vmcnt(6)
    } else if (i + 1 < niter){
      if constexpr (Q == 4) __builtin_amdgcn_s_waitcnt(0x0F74);  // vmcnt(4)
      else                  __builtin_amdgcn_s_waitcnt(0x0F73);  // vmcnt(3)
    } else {
      __builtin_amdgcn_s_waitcnt(0x0F70);                        // vmcnt(0)
    }
    __builtin_amdgcn_s_barrier();          // stage i resident for all waves
    const unsigned buf = (unsigned)i & 3u;
    bf16x8 af[4], bfr[NJ];
    #pragma unroll
    for (int ii = 0; ii < 4; ii++)  af[ii]  = ldsAB[buf][wr*4 + ii][lane];
    #pragma unroll
    for (int jj = 0; jj < NJ; jj++) bfr[jj] = ldsAB[buf][16 + wc*NJ + jj][lane];
    #pragma unroll
    for (int ii = 0; ii < 4; ii++)
      #pragma unroll
      for (int jj = 0; jj < NJ; jj++)
        acc[ii][jj] = __builtin_amdgcn_mfma_f32_16x16x32_bf16(af[ii], bfr[jj], acc[ii][jj], 0, 0, 0);
    __builtin_amdgcn_s_barrier();          // stage i consumed before its buffer is re-targeted
  }

  if (EPI == 4 && blockIdx.y == 2){
    // fused slice-softmax: this block's cols are the 256 logits (head h, g). One (row,head)'s
    // 32 logits live in 2 jj-frags x 16 lm lanes (same lq) -> shfl-xor reduce over masks 8/4/2/1.
    float* swp = (float*)outp2;
    #pragma unroll
    for (int ii = 0; ii < 4; ii++){
      int row0 = m0 + wr*64 + ii*16 + lq*4;
      #pragma unroll
      for (int hp = 0; hp < 4; hp++){
        int j0 = hp*2, j1 = j0 + 1;
        int h = wc*4 + hp;
        float b0 = bias[512 + wc*128 + j0*16 + lm];
        float b1 = bias[512 + wc*128 + j1*16 + lm];
        #pragma unroll
        for (int r = 0; r < 4; r++){
          int row = row0 + r;
          float v0 = acc[ii][j0][r] + b0;
          float v1 = acc[ii][j1][r] + b1;
          float mx = fmaxf(v0, v1);
          #pragma unroll
          for (int msk = 8; msk; msk >>= 1) mx = fmaxf(mx, __shfl_xor(mx, msk));
          float e0 = expf(v0 - mx), e1 = expf(v1 - mx);
          float ss = e0 + e1;
          #pragma unroll
          for (int msk = 8; msk; msk >>= 1) ss += __shfl_xor(ss, msk);
          float inv = 1.f / ss;
          int b = row >> 13, n = row & 8191;
          float* op = swp + ((size_t)(b*8 + h)*8192 + n)*32;
          op[lm]      = e0 * inv;
          op[16 + lm] = e1 * inv;
        }
      }
    }
    return;
  }

  #pragma unroll
  for (int ii = 0; ii < 4; ii++){
    int row0 = m0 + wr*64 + ii*16 + lq*4;
    #pragma unroll
    for (int jj = 0; jj < NJ; jj++){
      int col = n0 + wc*(BN/2) + jj*16 + lm;
      float bv = bias[col];
      #pragma unroll
      for (int r = 0; r < 4; r++){
        size_t idx = (size_t)(row0 + r)*N + col;
        float v = acc[ii][jj][r] + bv;
        if (EPI == 2) v += res[idx];
        if (EPI == 1) ((__bf16*)outp)[idx] = (__bf16)gelu_f(v);
        else          ((float*)outp)[idx]  = v;
      }
    }
  }
}

// ---------------- LayerNorm (512 cols), fp32 in -> bf16 out; 1 wave/row ----------------
__global__ __launch_bounds__(256) void ln_k(const float* __restrict__ x, const float* __restrict__ g,
                                            const float* __restrict__ b, __bf16* __restrict__ out)
{
  int w = threadIdx.x >> 6, lane = threadIdx.x & 63;
  int row = blockIdx.x*4 + w;
  const float* xr = x + (size_t)row*512 + lane*8;
  float v[8];
  *(f32x4*)&v[0] = *(const f32x4*)xr;
  *(f32x4*)&v[4] = *(const f32x4*)(xr + 4);
  float s = 0.f, sq = 0.f;
  #pragma unroll
  for (int e = 0; e < 8; e++){ s += v[e]; sq += v[e]*v[e]; }
  #pragma unroll
  for (int off = 32; off; off >>= 1){ s += __shfl_xor(s, off); sq += __shfl_xor(sq, off); }
  float mean = s * (1.f/512.f);
  float var  = sq * (1.f/512.f) - mean*mean;
  float rstd = rsqrtf(var + 1e-5f);
  float gv[8], bv[8];
  *(f32x4*)&gv[0] = *(const f32x4*)(g + lane*8);
  *(f32x4*)&gv[4] = *(const f32x4*)(g + lane*8 + 4);
  *(f32x4*)&bv[0] = *(const f32x4*)(b + lane*8);
  *(f32x4*)&bv[4] = *(const f32x4*)(b + lane*8 + 4);
  __bf16* op = out + (size_t)row*512 + lane*8;
  #pragma unroll
  for (int e = 0; e < 8; e++) op[e] = (__bf16)((v[e]-mean)*rstd*gv[e] + bv[e]);
}

// ---------------- token partial: per (chunk, bh) accumulate sw^T @ fx_mid over 512 n ----------------
__global__ __launch_bounds__(256) void token_part_k(const float* __restrict__ comb, const float* __restrict__ sw,
                                                    float* __restrict__ pt, float* __restrict__ ptm)
{
  __shared__ float fxl[32][64];
  __shared__ float swl[32][32];
  int t = threadIdx.x;
  int chunk = blockIdx.x, bh = blockIdx.y;
  int b = bh >> 3, h = bh & 7;
  int d = t & 63, gg = (t >> 6) * 8;
  float acc[8] = {0,0,0,0,0,0,0,0};
  float macc = 0.f;
  for (int s = 0; s < 16; s++){
    int nbase = chunk*512 + s*32;
    __syncthreads();
    #pragma unroll
    for (int i = 0; i < 2; i++){
      int e = t + 256*i; int rv = e >> 4, c4 = e & 15;
      *(f32x4*)&fxl[rv][c4*4] = *(const f32x4*)&comb[((size_t)b*8192 + nbase + rv)*768 + h*64 + c4*4];
    }
    { int rv = t >> 3, c4 = t & 7;
      *(f32x4*)&swl[rv][c4*4] = *(const f32x4*)&sw[((size_t)bh*8192 + nbase + rv)*32 + c4*4]; }
    __syncthreads();
    for (int nn = 0; nn < 32; nn++){
      float f = fxl[nn][d];
      #pragma unroll
      for (int jj = 0; jj < 8; jj++) acc[jj] += f * swl[nn][gg+jj];
    }
    if (t < 32){ for (int nn = 0; nn < 32; nn++) macc += swl[nn][t]; }
  }
  int cb = chunk*16 + bh;
  #pragma unroll
  for (int jj = 0; jj < 8; jj++)
    pt[((size_t)cb*32 + gg + jj)*64 + d] = acc[jj];
  if (t < 32) ptm[cb*32 + t] = macc;
}

// ---------------- token reduce + tiny attention per (b,h), fused ----------------
__global__ __launch_bounds__(256) void attn_k(const float* __restrict__ pt, const float* __restrict__ ptm,
                                              const float* __restrict__ Wq, const float* __restrict__ Wk,
                                              const float* __restrict__ Wv, float* __restrict__ ot)
{
  __shared__ float tok[32][64];
  __shared__ float ml[32];
  __shared__ float qq[32][65], kk2[32][65], vv[32][65];
  __shared__ float at[32][33];
  int t = threadIdx.x, bh = blockIdx.x;
  if (t < 32){
    float s = 0.f;
    for (int c = 0; c < 16; c++) s += ptm[(c*16 + bh)*32 + t];
    ml[t] = s + 1e-5f;
  }
  __syncthreads();
  #pragma unroll
  for (int i = 0; i < 8; i++){
    int e = t + 256*i; int g = e >> 6, d = e & 63;
    float s = 0.f;
    for (int c = 0; c < 16; c++) s += pt[((size_t)(c*16 + bh)*32 + g)*64 + d];
    tok[g][d] = s / ml[g];
  }
  __syncthreads();
  #pragma unroll
  for (int i = 0; i < 8; i++){
    int e = t + 256*i; int g = e >> 6, j = e & 63;
    float aq = 0.f, ak = 0.f, av = 0.f;
    for (int d = 0; d < 64; d++){
      float tv = tok[g][d];
      aq += tv * Wq[d*64 + j];
      ak += tv * Wk[d*64 + j];
      av += tv * Wv[d*64 + j];
    }
    qq[g][j] = aq; kk2[g][j] = ak; vv[g][j] = av;
  }
  __syncthreads();
  #pragma unroll
  for (int i = 0; i < 4; i++){
    int e = t + 256*i; int g = e >> 5, j2 = e & 31;
    float s2 = 0.f;
    for (int d = 0; d < 64; d++) s2 += qq[g][d] * kk2[j2][d];
    at[g][j2] = s2 * 0.125f;
  }
  __syncthreads();
  if (t < 32){
    float mx = at[t][0];
    for (int j = 1; j < 32; j++) mx = fmaxf(mx, at[t][j]);
    float ss = 0.f;
    for (int j = 0; j < 32; j++){ float e2 = expf(at[t][j]-mx); at[t][j] = e2; ss += e2; }
    float inv = 1.f / ss;
    for (int j = 0; j < 32; j++) at[t][j] *= inv;
  }
  __syncthreads();
  #pragma unroll
  for (int i = 0; i < 8; i++){
    int e = t + 256*i; int g = e >> 6, d = e & 63;
    float s3 = 0.f;
    for (int j = 0; j < 32; j++) s3 += at[g][j] * vv[j][d];
    ot[(size_t)bh*2048 + e] = s3;
  }
}

// ---------------- de-slice ----------------
__global__ __launch_bounds__(256) void deslice_k(const float* __restrict__ ot, const float* __restrict__ sw,
                                                 __bf16* __restrict__ outb)
{
  __shared__ float otl[32][64];
  __shared__ float swl[4][33];
  int t = threadIdx.x;
  int chunk = blockIdx.x, bh = blockIdx.y;
  int b = bh >> 3, h = bh & 7;
  #pragma unroll
  for (int i = 0; i < 8; i++){
    int e = t + 256*i;
    otl[e>>6][e&63] = ot[(size_t)bh*2048 + e];
  }
  int n0 = chunk*128;
  int nsub = t >> 6, d = t & 63;
  for (int s = 0; s < 32; s++){
    __syncthreads();
    if (t < 128) swl[t>>5][t&31] = sw[((size_t)bh*8192 + n0 + s*4 + (t>>5))*32 + (t&31)];
    __syncthreads();
    float a2 = 0.f;
    #pragma unroll
    for (int g = 0; g < 32; g++) a2 += otl[g][d] * swl[nsub][g];
    int n = n0 + s*4 + nsub;
    outb[((size_t)(b*8192 + n))*512 + h*64 + d] = (__bf16)a2;
  }
}

// ---------------- final head ----------------
__global__ __launch_bounds__(256) void head_k(const float* __restrict__ x, const float* __restrict__ g,
                                              const float* __restrict__ b, const float* __restrict__ Wout,
                                              const float* __restrict__ bout, float* __restrict__ out)
{
  int w = threadIdx.x >> 6, lane = threadIdx.x & 63;
  int row = blockIdx.x*4 + w;
  const float* xr = x + (size_t)row*512 + lane*8;
  float v[8];
  *(f32x4*)&v[0] = *(const f32x4*)xr;
  *(f32x4*)&v[4] = *(const f32x4*)(xr + 4);
  float s = 0.f, sq = 0.f;
  #pragma unroll
  for (int e = 0; e < 8; e++){ s += v[e]; sq += v[e]*v[e]; }
  #pragma unroll
  for (int off = 32; off; off >>= 1){ s += __shfl_xor(s, off); sq += __shfl_xor(sq, off); }
  float mean = s * (1.f/512.f);
  float rstd = rsqrtf(sq * (1.f/512.f) - mean*mean + 1e-5f);
  float o[4] = {0,0,0,0};
  #pragma unroll
  for (int e = 0; e < 8; e++){
    int c = lane*8 + e;
    float yn = (v[e]-mean)*rstd*g[c] + b[c];
    const float* wr = Wout + (size_t)c*4;
    o[0] += yn*wr[0]; o[1] += yn*wr[1]; o[2] += yn*wr[2]; o[3] += yn*wr[3];
  }
  #pragma unroll
  for (int off = 32; off; off >>= 1){
    #pragma unroll
    for (int j = 0; j < 4; j++) o[j] += __shfl_xor(o[j], off);
  }
  if (lane == 0){
    #pragma unroll
    for (int j = 0; j < 4; j++) out[(size_t)row*4 + j] = o[j] + bout[j];
  }
}

extern "C" void kernel_launch(void* const* d_in, const int* in_sizes, int n_in,
                              void* d_out, int out_size, void* d_ws, size_t ws_size,
                              hipStream_t stream)
{
  const float* fun    = (const float*)d_in[0];
  const float* emb    = (const float*)d_in[1];
  const float* W_pre1 = (const float*)d_in[2];
  const float* b_pre1 = (const float*)d_in[3];
  const float* W_pre2 = (const float*)d_in[4];
  const float* b_pre2 = (const float*)d_in[5];
  const float* placeholder = (const float*)d_in[6];
  const float* ln1_g  = (const float*)d_in[7];
  const float* ln1_b  = (const float*)d_in[8];
  const float* Wfx    = (const float*)d_in[9];
  const float* bfx    = (const float*)d_in[10];
  const float* Wx     = (const float*)d_in[11];
  const float* bx     = (const float*)d_in[12];
  const float* Wslice = (const float*)d_in[13];
  const float* bslice = (const float*)d_in[14];
  const float* temp   = (const float*)d_in[15];
  const float* Wq     = (const float*)d_in[16];
  const float* Wk     = (const float*)d_in[17];
  const float* Wv     = (const float*)d_in[18];
  const float* Wo     = (const float*)d_in[19];
  const float* bo     = (const float*)d_in[20];
  const float* ln2_g  = (const float*)d_in[21];
  const float* ln2_b  = (const float*)d_in[22];
  const float* Wm1    = (const float*)d_in[23];
  const float* bm1    = (const float*)d_in[24];
  const float* Wm2    = (const float*)d_in[25];
  const float* bm2    = (const float*)d_in[26];
  const float* lnf_g  = (const float*)d_in[27];
  const float* lnf_b  = (const float*)d_in[28];
  const float* Wout   = (const float*)d_in[29];
  const float* bout   = (const float*)d_in[30];

  char* ws = (char*)d_ws;
  float*  fx     = (float*)(ws + OFF_FX);
  __bf16* hbf    = (__bf16*)(ws + OFF_H);
  float*  comb   = (float*)(ws + OFF_COMB);
  float*  sw     = (float*)(ws + OFF_SW);
  __bf16* mlph   = (__bf16*)(ws + OFF_MLPH);
  __bf16* h1bf   = (__bf16*)(ws + OFF_H1);
  __bf16* outb   = (__bf16*)(ws + OFF_OUTB);
  float*  pt     = (float*)(ws + OFF_PT);
  float*  ptm    = (float*)(ws + OFF_PTM);
  float*  ot     = (float*)(ws + OFF_OT);
  __bf16* Wpre2t = (__bf16*)(ws + OFF_WT);
  __bf16* Btcat  = (__bf16*)(ws + OFF_WT + 1048576);
  __bf16* Wot    = (__bf16*)(ws + OFF_WT + 4194304);
  __bf16* Wm1t   = (__bf16*)(ws + OFF_WT + 6291456);
  __bf16* Wm2t   = (__bf16*)(ws + OFF_WT + 14680064);
  float*  bcat   = (float*)(ws + OFF_BIAS);
  float*  bpre2p = (float*)(ws + OFF_BIAS + 4*768*4);

  // ---- weight prep ----
  wtrans_k<<<dim3(16,8,1), 256,0,stream>>>(W_pre2, Wpre2t, 1024, 512, 0, 0);
  wtrans_k<<<dim3(8,8,4),  256,0,stream>>>(Wfx, Btcat, 512, 512, 262144, 393216);  // rows 0-511 of each cat
  wtrans_k<<<dim3(8,8,4),  256,0,stream>>>(Wo,  Wot,  512, 512, 262144, 262144);
  wtrans_k<<<dim3(8,32,4), 256,0,stream>>>(Wm1, Wm1t, 512, 2048, 1048576, 1048576);
  wtrans_k<<<dim3(32,8,4), 256,0,stream>>>(Wm2, Wm2t, 2048, 512, 1048576, 1048576);
  prep_wxs_k<<<dim3(256,4),128,0,stream>>>(Wx, Wslice, bx, bslice, temp, Btcat, bcat);
  bias_setup_k<<<10,256,0,stream>>>(b_pre2, placeholder, bfx, bpre2p, bcat);

  // ---- preprocess ----
  preproc1_k<<<4096,256,0,stream>>>(fun, emb, W_pre1, b_pre1, h1bf);
  // M=16384, N=512, K=1024 -> 256x128 tiles, grid 64x4
  gemm_wide<0,128><<<dim3(64,4),512,0,stream>>>(h1bf, Wpre2t, bpre2p, nullptr, (void*)fx, nullptr, 512, 10);

  // ---- layers ----
  for (int l = 0; l < 4; l++){
    ln_k<<<4096,256,0,stream>>>(fx, ln1_g + l*512, ln1_b + l*512, hbf);
    // N=768, K=512 -> 256x256 tiles, grid 64x3; y==2 block emits sw via fused softmax
    gemm_wide<4,256><<<dim3(64,3),512,0,stream>>>(hbf, Btcat + (size_t)l*393216, bcat + l*768, nullptr, (void*)comb, (void*)sw, 768, 9);
    token_part_k<<<dim3(16,16),256,0,stream>>>(comb, sw, pt, ptm);
    attn_k<<<16,256,0,stream>>>(pt, ptm, Wq + l*4096, Wk + l*4096, Wv + l*4096, ot);
    deslice_k<<<dim3(64,16),256,0,stream>>>(ot, sw, outb);
    // N=512, K=512 -> 256x128 tiles, grid 64x4
    gemm_wide<2,128><<<dim3(64,4),512,0,stream>>>(outb, Wot + (size_t)l*262144, bo + l*512, fx, (void*)fx, nullptr, 512, 9);
    ln_k<<<4096,256,0,stream>>>(fx, ln2_g + l*512, ln2_b + l*512, hbf);
    // N=2048, K=512 -> 256x256 tiles, grid 64x8
    gemm_wide<1,256><<<dim3(64,8),512,0,stream>>>(hbf, Wm1t + (size_t)l*1048576, bm1 + l*2048, nullptr, (void*)mlph, nullptr, 2048, 9);
    // N=512, K=2048 -> 256x128 tiles, grid 64x4
    gemm_wide<2,128><<<dim3(64,4),512,0,stream>>>(mlph, Wm2t + (size_t)l*1048576, bm2 + l*512, fx, (void*)fx, nullptr, 512, 11);
  }

  // ---- head ----
  head_k<<<4096,256,0,stream>>>(fx, lnf_g, lnf_b, Wout, bout, (float*)d_out);
}

// Round 9
// 1341.357 us; speedup vs baseline: 1.4364x; 1.0785x over previous
//
#include <hip/hip_runtime.h>
#include <hip/hip_bf16.h>
#include <cstdint>
#include <cstddef>

typedef float  f32x4  __attribute__((ext_vector_type(4)));
typedef __bf16 bf16x8 __attribute__((ext_vector_type(8)));
typedef __bf16 bf16x4 __attribute__((ext_vector_type(4)));

#define DEV __device__ __forceinline__

DEV float gelu_f(float x){ return 0.5f * x * (1.0f + erff(x * 0.70710678118654752f)); }

// async global->LDS, 16B/lane; LDS dest = wave-uniform base + lane*16
DEV void gl16(void* lds, const void* g){
  __builtin_amdgcn_global_load_lds((const __attribute__((address_space(1))) void*)g,
                                   (__attribute__((address_space(3))) void*)lds, 16, 0, 0);
}

// ---------------- workspace layout (bytes) ----------------
static constexpr size_t OFF_FX     = 0;                       // fx fp32 [16384,512]     33554432
static constexpr size_t OFF_H      = 33554432;                // h bf16 [16384,512]      16777216
static constexpr size_t OFF_REGA   = 50331648;                // 67108864 region
static constexpr size_t OFF_FXMID  = OFF_REGA;                // bf16 [16384,512]        16777216
static constexpr size_t OFF_SW     = OFF_REGA + 16777216;     // fp32 [16,8192,32]       16777216
static constexpr size_t OFF_MLPH   = OFF_REGA;                // bf16 [16384,2048] (after fxmid/sw dead)
static constexpr size_t OFF_H1     = OFF_REGA;                // bf16 [16384,1024] (preprocess only)
static constexpr size_t OFF_OUTB   = OFF_REGA + 67108864;     // bf16 [16384,512]        16777216
static constexpr size_t OFF_PT     = OFF_OUTB + 16777216;     // fp32 [16,16,32,64]      2097152
static constexpr size_t OFF_PTM    = OFF_PT + 2097152;        // fp32 [16,16,32]         32768
static constexpr size_t OFF_OT     = OFF_PTM + 32768;         // fp32 [16,32,64]         131072
static constexpr size_t OFF_WT     = OFF_OT + 131072;         // bf16 weights (22 MB)
static constexpr size_t OFF_BIAS   = OFF_WT + 23068672;       // bcat[4][768] f32, then bpre2p[512] f32

// ---------------- weight prep ----------------
__global__ __launch_bounds__(256) void wtrans_k(const float* __restrict__ W, __bf16* __restrict__ Wt,
                                                int K, int N, size_t wstride, size_t wtstride)
{
  __shared__ float tile[64][65];
  W  += (size_t)blockIdx.z * wstride;
  Wt += (size_t)blockIdx.z * wtstride;
  int t = threadIdx.x;
  int k0 = blockIdx.x * 64, n0 = blockIdx.y * 64;
  #pragma unroll
  for (int i = 0; i < 16; i++){
    int e = t + 256*i; int kk = e >> 6, nn = e & 63;
    tile[kk][nn] = W[(size_t)(k0+kk)*N + n0+nn];
  }
  __syncthreads();
  #pragma unroll
  for (int i = 0; i < 16; i++){
    int e = t + 256*i; int nn = e >> 6, kk = e & 63;
    Wt[(size_t)(n0+nn)*K + k0+kk] = (__bf16)tile[kk][nn];
  }
}

// Wxst -> rows 512+hg of Btcat[l]; blog -> bcat[l][512+hg]
__global__ __launch_bounds__(128) void prep_wxs_k(const float* __restrict__ Wx, const float* __restrict__ Wsl,
                                                  const float* __restrict__ bx, const float* __restrict__ bsl,
                                                  const float* __restrict__ temp,
                                                  __bf16* __restrict__ Btcat, float* __restrict__ bcat)
{
  __shared__ float wsc[64];
  int l = blockIdx.y;
  const float* Wx_l  = Wx  + (size_t)l*262144;
  const float* Wsl_l = Wsl + l*2048;
  const float* bx_l  = bx  + l*512;
  const float* bsl_l = bsl + l*32;
  __bf16* Wt_l = Btcat + (size_t)l*393216 + (size_t)512*512;
  float* blog_l = bcat + l*768 + 512;
  int hg = blockIdx.x; int h = hg >> 5, g = hg & 31;
  int t = threadIdx.x;
  if (t < 64) wsc[t] = Wsl_l[t*32 + g];
  __syncthreads();
  float invt = 1.0f / temp[l*8 + h];
  #pragma unroll
  for (int cc = 0; cc < 4; cc++){
    int c = t + cc*128;
    float a = 0.f;
    for (int d = 0; d < 64; d++) a += Wx_l[(size_t)c*512 + h*64 + d] * wsc[d];
    Wt_l[(size_t)hg*512 + c] = (__bf16)(a * invt);
  }
  if (t == 0){
    float a = 0.f;
    for (int d = 0; d < 64; d++) a += bx_l[h*64 + d] * wsc[d];
    blog_l[hg] = (a + bsl_l[g]) * invt;
  }
}

__global__ __launch_bounds__(256) void bias_setup_k(const float* __restrict__ b_pre2, const float* __restrict__ placeholder,
                                                    const float* __restrict__ bfx,
                                                    float* __restrict__ bpre2p, float* __restrict__ bcat)
{
  int i = blockIdx.x*256 + threadIdx.x;   // 0..2559
  if (i < 512) bpre2p[i] = b_pre2[i] + placeholder[i];
  else if (i < 2560){
    int j = i - 512; int l = j >> 9, c = j & 511;
    bcat[l*768 + c] = bfx[l*512 + c];
  }
}

// ---------------- preprocess stage 1 ----------------
__global__ __launch_bounds__(256) void preproc1_k(const float* __restrict__ fun, const float* __restrict__ emb,
                                                  const float* __restrict__ W1, const float* __restrict__ b1,
                                                  __bf16* __restrict__ h1)
{
  __shared__ float w1l[10][1024];
  int t = threadIdx.x;
  for (int i = t*4; i < 10240; i += 1024) *(f32x4*)&w1l[0][i] = *(const f32x4*)&W1[i];
  __syncthreads();
  f32x4 bv = *(const f32x4*)&b1[t*4];
  int r0 = blockIdx.x * 4;
  for (int r = 0; r < 4; r++){
    int m = r0 + r;
    const float* er = emb + (size_t)m*3;
    const float* fr = fun + (size_t)m*7;
    float x[10];
    x[0]=er[0]; x[1]=er[1]; x[2]=er[2];
    #pragma unroll
    for (int c = 0; c < 7; c++) x[3+c] = fr[c];
    f32x4 acc = bv;
    #pragma unroll
    for (int c = 0; c < 10; c++){
      f32x4 wv = *(const f32x4*)&w1l[c][t*4];
      acc += x[c] * wv;
    }
    __bf16* op = h1 + (size_t)m*1024 + t*4;
    #pragma unroll
    for (int e = 0; e < 4; e++) op[e] = (__bf16)gelu_f(acc[e]);
  }
}

// ---------------- wide-tile MFMA GEMM: 256xBN block (512 thr, 8 waves), triple-buffer depth-2 gl_lds ----------------
// R9: revert to R6's proven config (3 buffers, issue i+2, steady vmcnt(2Q)). Depth>=2 required
// (R7 depth-1 halved MfmaUtil); depth-3 neutral (R8). 1x8-wave block delivery caps ~5.7 B/cyc/CU.
// EPI: 0 = fp32 +bias | 1 = bf16 gelu | 2 = fp32 +bias+res
//      4 = comb: y<2 -> bf16 +bias (fx_mid, stride N=512); y==2 -> fused slice-softmax to sw (outp2)
template<int EPI, int BN>
__global__ __launch_bounds__(512) void gemm_wide(const __bf16* __restrict__ A, const __bf16* __restrict__ Bt,
                                                 const float* __restrict__ bias, const float* __restrict__ res,
                                                 void* __restrict__ outp, void* __restrict__ outp2,
                                                 int N, int lgK)
{
  constexpr int NSUB_B = BN/16;
  constexpr int S = 16 + NSUB_B;           // 32 (BN=256) or 24 (BN=128) subtiles per stage
  constexpr int Q = S/8;                   // gl16 per wave per stage: 4 or 3
  constexpr int NJ = BN/32;                // n-frags per wave: 8 or 4
  __shared__ bf16x8 ldsAB[3][S][64];       // [buf][subtile][lane]; 96KB / 72KB
  const int tid = threadIdx.x;
  const int w = tid >> 6, lane = tid & 63;
  const int lm = lane & 15, lq = lane >> 4;
  const int wr = w >> 1, wc = w & 1;       // wave grid 4x2; wave tile 64 x (BN/2)
  const int m0 = blockIdx.x * 256, n0 = blockIdx.y * BN;
  const int niter = 1 << (lgK - 5);

  auto issue = [&](int i){
    unsigned buf = (unsigned)i % 3u;
    int kk = i << 5;
    #pragma unroll
    for (int q = 0; q < Q; q++){
      int f = w*Q + q;                     // flat subtile index (wave-uniform)
      const __bf16* p = (f < 16)
        ? A  + (((size_t)(m0 + f*16 + lm)) << lgK) + kk + lq*8
        : Bt + (((size_t)(n0 + (f-16)*16 + lm)) << lgK) + kk + lq*8;
      gl16(&ldsAB[buf][f][0], p);
    }
  };

  issue(0); issue(1);

  f32x4 acc[4][NJ] = {};

  for (int i = 0; i < niter; ++i){
    if (i + 2 < niter){
      issue(i + 2);
      if constexpr (Q == 4) __builtin_amdgcn_s_waitcnt(0x0F78);  // vmcnt(8)
      else                  __builtin_amdgcn_s_waitcnt(0x0F76);  // vmcnt(6)
    } else if (i + 1 < niter){
      if constexpr (Q == 4) __builtin_amdgcn_s_waitcnt(0x0F74);  // vmcnt(4)
      else                  __builtin_amdgcn_s_waitcnt(0x0F73);  // vmcnt(3)
    } else {
      __builtin_amdgcn_s_waitcnt(0x0F70);                        // vmcnt(0)
    }
    __builtin_amdgcn_s_barrier();          // stage i resident for all waves
    const unsigned buf = (unsigned)i % 3u;
    bf16x8 af[4], bfr[NJ];
    #pragma unroll
    for (int ii = 0; ii < 4; ii++)  af[ii]  = ldsAB[buf][wr*4 + ii][lane];
    #pragma unroll
    for (int jj = 0; jj < NJ; jj++) bfr[jj] = ldsAB[buf][16 + wc*NJ + jj][lane];
    #pragma unroll
    for (int ii = 0; ii < 4; ii++)
      #pragma unroll
      for (int jj = 0; jj < NJ; jj++)
        acc[ii][jj] = __builtin_amdgcn_mfma_f32_16x16x32_bf16(af[ii], bfr[jj], acc[ii][jj], 0, 0, 0);
    __builtin_amdgcn_s_barrier();          // stage i consumed before its buffer is re-targeted
  }

  if (EPI == 4 && blockIdx.y == 2){
    // fused slice-softmax: this block's cols are the 256 logits (head h, g). One (row,head)'s
    // 32 logits live in 2 jj-frags x 16 lm lanes (same lq) -> shfl-xor reduce over masks 8/4/2/1.
    float* swp = (float*)outp2;
    #pragma unroll
    for (int ii = 0; ii < 4; ii++){
      int row0 = m0 + wr*64 + ii*16 + lq*4;
      #pragma unroll
      for (int hp = 0; hp < 4; hp++){
        int j0 = hp*2, j1 = j0 + 1;
        int h = wc*4 + hp;
        float b0 = bias[512 + wc*128 + j0*16 + lm];
        float b1 = bias[512 + wc*128 + j1*16 + lm];
        #pragma unroll
        for (int r = 0; r < 4; r++){
          int row = row0 + r;
          float v0 = acc[ii][j0][r] + b0;
          float v1 = acc[ii][j1][r] + b1;
          float mx = fmaxf(v0, v1);
          #pragma unroll
          for (int msk = 8; msk; msk >>= 1) mx = fmaxf(mx, __shfl_xor(mx, msk));
          float e0 = expf(v0 - mx), e1 = expf(v1 - mx);
          float ss = e0 + e1;
          #pragma unroll
          for (int msk = 8; msk; msk >>= 1) ss += __shfl_xor(ss, msk);
          float inv = 1.f / ss;
          int b = row >> 13, n = row & 8191;
          float* op = swp + ((size_t)(b*8 + h)*8192 + n)*32;
          op[lm]      = e0 * inv;
          op[16 + lm] = e1 * inv;
        }
      }
    }
    return;
  }

  #pragma unroll
  for (int ii = 0; ii < 4; ii++){
    int row0 = m0 + wr*64 + ii*16 + lq*4;
    #pragma unroll
    for (int jj = 0; jj < NJ; jj++){
      int col = n0 + wc*(BN/2) + jj*16 + lm;
      float bv = bias[col];
      #pragma unroll
      for (int r = 0; r < 4; r++){
        size_t idx = (size_t)(row0 + r)*N + col;
        float v = acc[ii][jj][r] + bv;
        if (EPI == 2) v += res[idx];
        if (EPI == 1)      ((__bf16*)outp)[idx] = (__bf16)gelu_f(v);
        else if (EPI == 4) ((__bf16*)outp)[idx] = (__bf16)v;     // fx_mid bf16
        else               ((float*)outp)[idx]  = v;
      }
    }
  }
}

// ---------------- LayerNorm (512 cols), fp32 in -> bf16 out; 1 wave/row ----------------
__global__ __launch_bounds__(256) void ln_k(const float* __restrict__ x, const float* __restrict__ g,
                                            const float* __restrict__ b, __bf16* __restrict__ out)
{
  int w = threadIdx.x >> 6, lane = threadIdx.x & 63;
  int row = blockIdx.x*4 + w;
  const float* xr = x + (size_t)row*512 + lane*8;
  float v[8];
  *(f32x4*)&v[0] = *(const f32x4*)xr;
  *(f32x4*)&v[4] = *(const f32x4*)(xr + 4);
  float s = 0.f, sq = 0.f;
  #pragma unroll
  for (int e = 0; e < 8; e++){ s += v[e]; sq += v[e]*v[e]; }
  #pragma unroll
  for (int off = 32; off; off >>= 1){ s += __shfl_xor(s, off); sq += __shfl_xor(sq, off); }
  float mean = s * (1.f/512.f);
  float var  = sq * (1.f/512.f) - mean*mean;
  float rstd = rsqrtf(var + 1e-5f);
  float gv[8], bv[8];
  *(f32x4*)&gv[0] = *(const f32x4*)(g + lane*8);
  *(f32x4*)&gv[4] = *(const f32x4*)(g + lane*8 + 4);
  *(f32x4*)&bv[0] = *(const f32x4*)(b + lane*8);
  *(f32x4*)&bv[4] = *(const f32x4*)(b + lane*8 + 4);
  __bf16* op = out + (size_t)row*512 + lane*8;
  #pragma unroll
  for (int e = 0; e < 8; e++) op[e] = (__bf16)((v[e]-mean)*rstd*gv[e] + bv[e]);
}

// ---------------- token partial: per (chunk, bh) accumulate sw^T @ fx_mid over 512 n (fx_mid bf16) ----------------
__global__ __launch_bounds__(256) void token_part_k(const __bf16* __restrict__ fxmid, const float* __restrict__ sw,
                                                    float* __restrict__ pt, float* __restrict__ ptm)
{
  __shared__ float fxl[32][64];
  __shared__ float swl[32][32];
  int t = threadIdx.x;
  int chunk = blockIdx.x, bh = blockIdx.y;
  int b = bh >> 3, h = bh & 7;
  int d = t & 63, gg = (t >> 6) * 8;
  float acc[8] = {0,0,0,0,0,0,0,0};
  float macc = 0.f;
  for (int s = 0; s < 16; s++){
    int nbase = chunk*512 + s*32;
    __syncthreads();
    #pragma unroll
    for (int i = 0; i < 2; i++){
      int e = t + 256*i; int rv = e >> 4, c4 = e & 15;
      bf16x4 v = *(const bf16x4*)&fxmid[((size_t)(b*8192 + nbase + rv))*512 + h*64 + c4*4];
      fxl[rv][c4*4+0] = (float)v[0];
      fxl[rv][c4*4+1] = (float)v[1];
      fxl[rv][c4*4+2] = (float)v[2];
      fxl[rv][c4*4+3] = (float)v[3];
    }
    { int rv = t >> 3, c4 = t & 7;
      *(f32x4*)&swl[rv][c4*4] = *(const f32x4*)&sw[((size_t)bh*8192 + nbase + rv)*32 + c4*4]; }
    __syncthreads();
    for (int nn = 0; nn < 32; nn++){
      float f = fxl[nn][d];
      #pragma unroll
      for (int jj = 0; jj < 8; jj++) acc[jj] += f * swl[nn][gg+jj];
    }
    if (t < 32){ for (int nn = 0; nn < 32; nn++) macc += swl[nn][t]; }
  }
  int cb = chunk*16 + bh;
  #pragma unroll
  for (int jj = 0; jj < 8; jj++)
    pt[((size_t)cb*32 + gg + jj)*64 + d] = acc[jj];
  if (t < 32) ptm[cb*32 + t] = macc;
}

// ---------------- token reduce + tiny attention per (b,h), fused ----------------
__global__ __launch_bounds__(256) void attn_k(const float* __restrict__ pt, const float* __restrict__ ptm,
                                              const float* __restrict__ Wq, const float* __restrict__ Wk,
                                              const float* __restrict__ Wv, float* __restrict__ ot)
{
  __shared__ float tok[32][64];
  __shared__ float ml[32];
  __shared__ float qq[32][65], kk2[32][65], vv[32][65];
  __shared__ float at[32][33];
  int t = threadIdx.x, bh = blockIdx.x;
  if (t < 32){
    float s = 0.f;
    for (int c = 0; c < 16; c++) s += ptm[(c*16 + bh)*32 + t];
    ml[t] = s + 1e-5f;
  }
  __syncthreads();
  #pragma unroll
  for (int i = 0; i < 8; i++){
    int e = t + 256*i; int g = e >> 6, d = e & 63;
    float s = 0.f;
    for (int c = 0; c < 16; c++) s += pt[((size_t)(c*16 + bh)*32 + g)*64 + d];
    tok[g][d] = s / ml[g];
  }
  __syncthreads();
  #pragma unroll
  for (int i = 0; i < 8; i++){
    int e = t + 256*i; int g = e >> 6, j = e & 63;
    float aq = 0.f, ak = 0.f, av = 0.f;
    for (int d = 0; d < 64; d++){
      float tv = tok[g][d];
      aq += tv * Wq[d*64 + j];
      ak += tv * Wk[d*64 + j];
      av += tv * Wv[d*64 + j];
    }
    qq[g][j] = aq; kk2[g][j] = ak; vv[g][j] = av;
  }
  __syncthreads();
  #pragma unroll
  for (int i = 0; i < 4; i++){
    int e = t + 256*i; int g = e >> 5, j2 = e & 31;
    float s2 = 0.f;
    for (int d = 0; d < 64; d++) s2 += qq[g][d] * kk2[j2][d];
    at[g][j2] = s2 * 0.125f;
  }
  __syncthreads();
  if (t < 32){
    float mx = at[t][0];
    for (int j = 1; j < 32; j++) mx = fmaxf(mx, at[t][j]);
    float ss = 0.f;
    for (int j = 0; j < 32; j++){ float e2 = expf(at[t][j]-mx); at[t][j] = e2; ss += e2; }
    float inv = 1.f / ss;
    for (int j = 0; j < 32; j++) at[t][j] *= inv;
  }
  __syncthreads();
  #pragma unroll
  for (int i = 0; i < 8; i++){
    int e = t + 256*i; int g = e >> 6, d = e & 63;
    float s3 = 0.f;
    for (int j = 0; j < 32; j++) s3 += at[g][j] * vv[j][d];
    ot[(size_t)bh*2048 + e] = s3;
  }
}

// ---------------- de-slice (rewritten): 1 barrier, hoisted ot-frags, bf16x4 stores ----------------
// out[b, n, h*64+d] = sum_g ot[bh][g][d] * sw[bh][n][g];  block = (chunk of 128 n) x bh
__global__ __launch_bounds__(256) void deslice_k(const float* __restrict__ ot, const float* __restrict__ sw,
                                                 __bf16* __restrict__ outb)
{
  __shared__ float otl[32][64];
  __shared__ float swl[128][36];           // pad 36 keeps f32x4 stores aligned, rows 4-aligned
  int t = threadIdx.x;
  int chunk = blockIdx.x, bh = blockIdx.y;
  int b = bh >> 3, h = bh & 7;
  int n0 = chunk*128;
  #pragma unroll
  for (int i = 0; i < 8; i++){
    int e = t + 256*i;
    otl[e>>6][e&63] = ot[(size_t)bh*2048 + e];
  }
  {
    int r = t >> 1, half = t & 1;          // each thread loads 16 floats of one sw row
    const float* sp = sw + ((size_t)bh*8192 + n0 + r)*32 + half*16;
    float* dp = &swl[r][half*16];
    #pragma unroll
    for (int q = 0; q < 4; q++) *(f32x4*)(dp + q*4) = *(const f32x4*)(sp + q*4);
  }
  __syncthreads();
  const int nl = t >> 4;                   // base row (16 rows per pass, 8 passes)
  const int d0 = (t & 15) * 4;
  float o[8][4] = {};
  for (int g = 0; g < 32; g++){
    f32x4 ov = *(const f32x4*)&otl[g][d0];
    #pragma unroll
    for (int p = 0; p < 8; p++){
      float s = swl[p*16 + nl][g];
      o[p][0] += s * ov[0]; o[p][1] += s * ov[1];
      o[p][2] += s * ov[2]; o[p][3] += s * ov[3];
    }
  }
  #pragma unroll
  for (int p = 0; p < 8; p++){
    int n = n0 + p*16 + nl;
    bf16x4 v;
    v[0] = (__bf16)o[p][0]; v[1] = (__bf16)o[p][1];
    v[2] = (__bf16)o[p][2]; v[3] = (__bf16)o[p][3];
    *(bf16x4*)&outb[((size_t)(b*8192 + n))*512 + h*64 + d0] = v;
  }
}

// ---------------- final head ----------------
__global__ __launch_bounds__(256) void head_k(const float* __restrict__ x, const float* __restrict__ g,
                                              const float* __restrict__ b, const float* __restrict__ Wout,
                                              const float* __restrict__ bout, float* __restrict__ out)
{
  int w = threadIdx.x >> 6, lane = threadIdx.x & 63;
  int row = blockIdx.x*4 + w;
  const float* xr = x + (size_t)row*512 + lane*8;
  float v[8];
  *(f32x4*)&v[0] = *(const f32x4*)xr;
  *(f32x4*)&v[4] = *(const f32x4*)(xr + 4);
  float s = 0.f, sq = 0.f;
  #pragma unroll
  for (int e = 0; e < 8; e++){ s += v[e]; sq += v[e]*v[e]; }
  #pragma unroll
  for (int off = 32; off; off >>= 1){ s += __shfl_xor(s, off); sq += __shfl_xor(sq, off); }
  float mean = s * (1.f/512.f);
  float rstd = rsqrtf(sq * (1.f/512.f) - mean*mean + 1e-5f);
  float o[4] = {0,0,0,0};
  #pragma unroll
  for (int e = 0; e < 8; e++){
    int c = lane*8 + e;
    float yn = (v[e]-mean)*rstd*g[c] + b[c];
    const float* wr = Wout + (size_t)c*4;
    o[0] += yn*wr[0]; o[1] += yn*wr[1]; o[2] += yn*wr[2]; o[3] += yn*wr[3];
  }
  #pragma unroll
  for (int off = 32; off; off >>= 1){
    #pragma unroll
    for (int j = 0; j < 4; j++) o[j] += __shfl_xor(o[j], off);
  }
  if (lane == 0){
    #pragma unroll
    for (int j = 0; j < 4; j++) out[(size_t)row*4 + j] = o[j] + bout[j];
  }
}

extern "C" void kernel_launch(void* const* d_in, const int* in_sizes, int n_in,
                              void* d_out, int out_size, void* d_ws, size_t ws_size,
                              hipStream_t stream)
{
  const float* fun    = (const float*)d_in[0];
  const float* emb    = (const float*)d_in[1];
  const float* W_pre1 = (const float*)d_in[2];
  const float* b_pre1 = (const float*)d_in[3];
  const float* W_pre2 = (const float*)d_in[4];
  const float* b_pre2 = (const float*)d_in[5];
  const float* placeholder = (const float*)d_in[6];
  const float* ln1_g  = (const float*)d_in[7];
  const float* ln1_b  = (const float*)d_in[8];
  const float* Wfx    = (const float*)d_in[9];
  const float* bfx    = (const float*)d_in[10];
  const float* Wx     = (const float*)d_in[11];
  const float* bx     = (const float*)d_in[12];
  const float* Wslice = (const float*)d_in[13];
  const float* bslice = (const float*)d_in[14];
  const float* temp   = (const float*)d_in[15];
  const float* Wq     = (const float*)d_in[16];
  const float* Wk     = (const float*)d_in[17];
  const float* Wv     = (const float*)d_in[18];
  const float* Wo     = (const float*)d_in[19];
  const float* bo     = (const float*)d_in[20];
  const float* ln2_g  = (const float*)d_in[21];
  const float* ln2_b  = (const float*)d_in[22];
  const float* Wm1    = (const float*)d_in[23];
  const float* bm1    = (const float*)d_in[24];
  const float* Wm2    = (const float*)d_in[25];
  const float* bm2    = (const float*)d_in[26];
  const float* lnf_g  = (const float*)d_in[27];
  const float* lnf_b  = (const float*)d_in[28];
  const float* Wout   = (const float*)d_in[29];
  const float* bout   = (const float*)d_in[30];

  char* ws = (char*)d_ws;
  float*  fx     = (float*)(ws + OFF_FX);
  __bf16* hbf    = (__bf16*)(ws + OFF_H);
  __bf16* fxmid  = (__bf16*)(ws + OFF_FXMID);
  float*  sw     = (float*)(ws + OFF_SW);
  __bf16* mlph   = (__bf16*)(ws + OFF_MLPH);
  __bf16* h1bf   = (__bf16*)(ws + OFF_H1);
  __bf16* outb   = (__bf16*)(ws + OFF_OUTB);
  float*  pt     = (float*)(ws + OFF_PT);
  float*  ptm    = (float*)(ws + OFF_PTM);
  float*  ot     = (float*)(ws + OFF_OT);
  __bf16* Wpre2t = (__bf16*)(ws + OFF_WT);
  __bf16* Btcat  = (__bf16*)(ws + OFF_WT + 1048576);
  __bf16* Wot    = (__bf16*)(ws + OFF_WT + 4194304);
  __bf16* Wm1t   = (__bf16*)(ws + OFF_WT + 6291456);
  __bf16* Wm2t   = (__bf16*)(ws + OFF_WT + 14680064);
  float*  bcat   = (float*)(ws + OFF_BIAS);
  float*  bpre2p = (float*)(ws + OFF_BIAS + 4*768*4);

  // ---- weight prep ----
  wtrans_k<<<dim3(16,8,1), 256,0,stream>>>(W_pre2, Wpre2t, 1024, 512, 0, 0);
  wtrans_k<<<dim3(8,8,4),  256,0,stream>>>(Wfx, Btcat, 512, 512, 262144, 393216);  // rows 0-511 of each cat
  wtrans_k<<<dim3(8,8,4),  256,0,stream>>>(Wo,  Wot,  512, 512, 262144, 262144);
  wtrans_k<<<dim3(8,32,4), 256,0,stream>>>(Wm1, Wm1t, 512, 2048, 1048576, 1048576);
  wtrans_k<<<dim3(32,8,4), 256,0,stream>>>(Wm2, Wm2t, 2048, 512, 1048576, 1048576);
  prep_wxs_k<<<dim3(256,4),128,0,stream>>>(Wx, Wslice, bx, bslice, temp, Btcat, bcat);
  bias_setup_k<<<10,256,0,stream>>>(b_pre2, placeholder, bfx, bpre2p, bcat);

  // ---- preprocess ----
  preproc1_k<<<4096,256,0,stream>>>(fun, emb, W_pre1, b_pre1, h1bf);
  // M=16384, N=512, K=1024 -> 256x128 tiles, grid 64x4
  gemm_wide<0,128><<<dim3(64,4),512,0,stream>>>(h1bf, Wpre2t, bpre2p, nullptr, (void*)fx, nullptr, 512, 10);

  // ---- layers ----
  for (int l = 0; l < 4; l++){
    ln_k<<<4096,256,0,stream>>>(fx, ln1_g + l*512, ln1_b + l*512, hbf);
    // K=512 -> 256x256 tiles, grid 64x3; y<2 write fx_mid bf16 (stride 512), y==2 fused softmax -> sw
    gemm_wide<4,256><<<dim3(64,3),512,0,stream>>>(hbf, Btcat + (size_t)l*393216, bcat + l*768, nullptr, (void*)fxmid, (void*)sw, 512, 9);
    token_part_k<<<dim3(16,16),256,0,stream>>>(fxmid, sw, pt, ptm);
    attn_k<<<16,256,0,stream>>>(pt, ptm, Wq + l*4096, Wk + l*4096, Wv + l*4096, ot);
    deslice_k<<<dim3(64,16),256,0,stream>>>(ot, sw, outb);
    // N=512, K=512 -> 256x128 tiles, grid 64x4
    gemm_wide<2,128><<<dim3(64,4),512,0,stream>>>(outb, Wot + (size_t)l*262144, bo + l*512, fx, (void*)fx, nullptr, 512, 9);
    ln_k<<<4096,256,0,stream>>>(fx, ln2_g + l*512, ln2_b + l*512, hbf);
    // N=2048, K=512 -> 256x256 tiles, grid 64x8
    gemm_wide<1,256><<<dim3(64,8),512,0,stream>>>(hbf, Wm1t + (size_t)l*1048576, bm1 + l*2048, nullptr, (void*)mlph, nullptr, 2048, 9);
    // N=512, K=2048 -> 256x128 tiles, grid 64x4
    gemm_wide<2,128><<<dim3(64,4),512,0,stream>>>(mlph, Wm2t + (size_t)l*1048576, bm2 + l*512, fx, (void*)fx, nullptr, 512, 11);
  }

  // ---- head ----
  head_k<<<4096,256,0,stream>>>(fx, lnf_g, lnf_b, Wout, bout, (float*)d_out);
}

// Round 10
// 1334.167 us; speedup vs baseline: 1.4442x; 1.0054x over previous
//
#include <hip/hip_runtime.h>
#include <hip/hip_bf16.h>
#include <cstdint>
#include <cstddef>

typedef float  f32x4  __attribute__((ext_vector_type(4)));
typedef __bf16 bf16x8 __attribute__((ext_vector_type(8)));
typedef __bf16 bf16x4 __attribute__((ext_vector_type(4)));

#define DEV __device__ __forceinline__

DEV float gelu_f(float x){ return 0.5f * x * (1.0f + erff(x * 0.70710678118654752f)); }

// s_waitcnt imm (gfx9 enc): vmcnt[3:0]|[15:14], expcnt[6:4], lgkmcnt[11:8]
#define WAIT_LGKM0 0xC07F   // lgkmcnt(0), vm/exp no-wait

// ---------------- workspace layout (bytes) ----------------
static constexpr size_t OFF_FX     = 0;                       // fx fp32 [16384,512]     33554432
static constexpr size_t OFF_H      = 33554432;                // h bf16 [16384,512]      16777216
static constexpr size_t OFF_REGA   = 50331648;                // 67108864 region
static constexpr size_t OFF_FXMID  = OFF_REGA;                // bf16 [16384,512]        16777216
static constexpr size_t OFF_SW     = OFF_REGA + 16777216;     // fp32 [16,8192,32]       16777216
static constexpr size_t OFF_MLPH   = OFF_REGA;                // bf16 [16384,2048] (after fxmid/sw dead)
static constexpr size_t OFF_H1     = OFF_REGA;                // bf16 [16384,1024] (preprocess only)
static constexpr size_t OFF_OUTB   = OFF_REGA + 67108864;     // bf16 [16384,512]        16777216
static constexpr size_t OFF_PT     = OFF_OUTB + 16777216;     // fp32 [16,16,32,64]      2097152
static constexpr size_t OFF_PTM    = OFF_PT + 2097152;        // fp32 [16,16,32]         32768
static constexpr size_t OFF_OT     = OFF_PTM + 32768;         // fp32 [16,32,64]         131072
static constexpr size_t OFF_WT     = OFF_OT + 131072;         // bf16 weights (22 MB)
static constexpr size_t OFF_BIAS   = OFF_WT + 23068672;       // bcat[4][768] f32, then bpre2p[512] f32

// ---------------- weight prep ----------------
__global__ __launch_bounds__(256) void wtrans_k(const float* __restrict__ W, __bf16* __restrict__ Wt,
                                                int K, int N, size_t wstride, size_t wtstride)
{
  __shared__ float tile[64][65];
  W  += (size_t)blockIdx.z * wstride;
  Wt += (size_t)blockIdx.z * wtstride;
  int t = threadIdx.x;
  int k0 = blockIdx.x * 64, n0 = blockIdx.y * 64;
  #pragma unroll
  for (int i = 0; i < 16; i++){
    int e = t + 256*i; int kk = e >> 6, nn = e & 63;
    tile[kk][nn] = W[(size_t)(k0+kk)*N + n0+nn];
  }
  __syncthreads();
  #pragma unroll
  for (int i = 0; i < 16; i++){
    int e = t + 256*i; int nn = e >> 6, kk = e & 63;
    Wt[(size_t)(n0+nn)*K + k0+kk] = (__bf16)tile[kk][nn];
  }
}

// Wxst -> rows 512+hg of Btcat[l]; blog -> bcat[l][512+hg]
__global__ __launch_bounds__(128) void prep_wxs_k(const float* __restrict__ Wx, const float* __restrict__ Wsl,
                                                  const float* __restrict__ bx, const float* __restrict__ bsl,
                                                  const float* __restrict__ temp,
                                                  __bf16* __restrict__ Btcat, float* __restrict__ bcat)
{
  __shared__ float wsc[64];
  int l = blockIdx.y;
  const float* Wx_l  = Wx  + (size_t)l*262144;
  const float* Wsl_l = Wsl + l*2048;
  const float* bx_l  = bx  + l*512;
  const float* bsl_l = bsl + l*32;
  __bf16* Wt_l = Btcat + (size_t)l*393216 + (size_t)512*512;
  float* blog_l = bcat + l*768 + 512;
  int hg = blockIdx.x; int h = hg >> 5, g = hg & 31;
  int t = threadIdx.x;
  if (t < 64) wsc[t] = Wsl_l[t*32 + g];
  __syncthreads();
  float invt = 1.0f / temp[l*8 + h];
  #pragma unroll
  for (int cc = 0; cc < 4; cc++){
    int c = t + cc*128;
    float a = 0.f;
    for (int d = 0; d < 64; d++) a += Wx_l[(size_t)c*512 + h*64 + d] * wsc[d];
    Wt_l[(size_t)hg*512 + c] = (__bf16)(a * invt);
  }
  if (t == 0){
    float a = 0.f;
    for (int d = 0; d < 64; d++) a += bx_l[h*64 + d] * wsc[d];
    blog_l[hg] = (a + bsl_l[g]) * invt;
  }
}

__global__ __launch_bounds__(256) void bias_setup_k(const float* __restrict__ b_pre2, const float* __restrict__ placeholder,
                                                    const float* __restrict__ bfx,
                                                    float* __restrict__ bpre2p, float* __restrict__ bcat)
{
  int i = blockIdx.x*256 + threadIdx.x;   // 0..2559
  if (i < 512) bpre2p[i] = b_pre2[i] + placeholder[i];
  else if (i < 2560){
    int j = i - 512; int l = j >> 9, c = j & 511;
    bcat[l*768 + c] = bfx[l*512 + c];
  }
}

// ---------------- preprocess stage 1 ----------------
__global__ __launch_bounds__(256) void preproc1_k(const float* __restrict__ fun, const float* __restrict__ emb,
                                                  const float* __restrict__ W1, const float* __restrict__ b1,
                                                  __bf16* __restrict__ h1)
{
  __shared__ float w1l[10][1024];
  int t = threadIdx.x;
  for (int i = t*4; i < 10240; i += 1024) *(f32x4*)&w1l[0][i] = *(const f32x4*)&W1[i];
  __syncthreads();
  f32x4 bv = *(const f32x4*)&b1[t*4];
  int r0 = blockIdx.x * 4;
  for (int r = 0; r < 4; r++){
    int m = r0 + r;
    const float* er = emb + (size_t)m*3;
    const float* fr = fun + (size_t)m*7;
    float x[10];
    x[0]=er[0]; x[1]=er[1]; x[2]=er[2];
    #pragma unroll
    for (int c = 0; c < 7; c++) x[3+c] = fr[c];
    f32x4 acc = bv;
    #pragma unroll
    for (int c = 0; c < 10; c++){
      f32x4 wv = *(const f32x4*)&w1l[c][t*4];
      acc += x[c] * wv;
    }
    __bf16* op = h1 + (size_t)m*1024 + t*4;
    #pragma unroll
    for (int e = 0; e < 4; e++) op[e] = (__bf16)gelu_f(acc[e]);
  }
}

// ---------------- wide-tile MFMA GEMM: 256xBN block (512 thr, 8 waves), reg-prefetch staging ----------------
// R10: gl_lds requests serialize per block (~350 cy each -> 5.7 B/cyc cap at 1 block/CU; R6-R9
// evidence). Regular per-wave loads pipeline to ~10 B/cyc (R3 measured 9.8 at 128-tile). So:
// stage via bf16x8 global loads into VGPRs (issued one stage ahead) + ds_write_b128 ping/pong.
// EPI: 0 = fp32 +bias | 1 = bf16 gelu | 2 = fp32 +bias+res
//      4 = comb: y<2 -> bf16 +bias (fx_mid, stride N=512); y==2 -> fused slice-softmax to sw (outp2)
template<int EPI, int BN>
__global__ __launch_bounds__(512) void gemm_wide(const __bf16* __restrict__ A, const __bf16* __restrict__ Bt,
                                                 const float* __restrict__ bias, const float* __restrict__ res,
                                                 void* __restrict__ outp, void* __restrict__ outp2,
                                                 int N, int lgK)
{
  constexpr int NSUB_B = BN/16;
  constexpr int S = 16 + NSUB_B;           // 32 (BN=256) or 24 (BN=128) subtiles per stage
  constexpr int Q = S/8;                   // subtiles staged per wave: 4 or 3
  constexpr int NJ = BN/32;                // n-frags per wave: 8 or 4
  __shared__ bf16x8 ldsAB[2][S][64];       // [buf][subtile][lane]; 64KB / 48KB
  const int tid = threadIdx.x;
  const int w = tid >> 6, lane = tid & 63;
  const int lm = lane & 15, lq = lane >> 4;
  const int wr = w >> 1, wc = w & 1;       // wave grid 4x2; wave tile 64 x (BN/2)
  const int m0 = blockIdx.x * 256, n0 = blockIdx.y * BN;
  const int niter = 1 << (lgK - 5);

  // per-q staging pointers: subtile f = w*Q+q; row = (f<16 ? A m-row : Bt n-row) + lm; k-off lq*8
  const __bf16* gp[Q];
  #pragma unroll
  for (int q = 0; q < Q; q++){
    int f = w*Q + q;
    gp[q] = (f < 16)
      ? A  + (((size_t)(m0 + f*16 + lm)) << lgK) + lq*8
      : Bt + (((size_t)(n0 + (f-16)*16 + lm)) << lgK) + lq*8;
  }

  // preload stage 0 into registers
  bf16x8 r[Q];
  #pragma unroll
  for (int q = 0; q < Q; q++){ r[q] = *(const bf16x8*)gp[q]; gp[q] += 32; }

  f32x4 acc[4][NJ] = {};

  for (int i = 0; i < niter; ++i){
    __builtin_amdgcn_s_barrier();            // prev stage's ds_reads complete (buf reuse safe)
    const unsigned buf = (unsigned)i & 1u;
    #pragma unroll
    for (int q = 0; q < Q; q++)              // ds_write_b128; compiler inserts vmcnt wait for r[]
      ldsAB[buf][w*Q + q][lane] = r[q];
    if (i + 1 < niter){                      // issue next stage's loads (no wait)
      #pragma unroll
      for (int q = 0; q < Q; q++){ r[q] = *(const bf16x8*)gp[q]; gp[q] += 32; }
    }
    __builtin_amdgcn_s_waitcnt(WAIT_LGKM0);  // own ds_writes visible
    __builtin_amdgcn_s_barrier();            // everyone's writes visible
    bf16x8 af[4], bfr[NJ];
    #pragma unroll
    for (int ii = 0; ii < 4; ii++)  af[ii]  = ldsAB[buf][wr*4 + ii][lane];
    #pragma unroll
    for (int jj = 0; jj < NJ; jj++) bfr[jj] = ldsAB[buf][16 + wc*NJ + jj][lane];
    #pragma unroll
    for (int ii = 0; ii < 4; ii++)
      #pragma unroll
      for (int jj = 0; jj < NJ; jj++)
        acc[ii][jj] = __builtin_amdgcn_mfma_f32_16x16x32_bf16(af[ii], bfr[jj], acc[ii][jj], 0, 0, 0);
  }

  if (EPI == 4 && blockIdx.y == 2){
    // fused slice-softmax: this block's cols are the 256 logits (head h, g). One (row,head)'s
    // 32 logits live in 2 jj-frags x 16 lm lanes (same lq) -> shfl-xor reduce over masks 8/4/2/1.
    float* swp = (float*)outp2;
    #pragma unroll
    for (int ii = 0; ii < 4; ii++){
      int row0 = m0 + wr*64 + ii*16 + lq*4;
      #pragma unroll
      for (int hp = 0; hp < 4; hp++){
        int j0 = hp*2, j1 = j0 + 1;
        int h = wc*4 + hp;
        float b0 = bias[512 + wc*128 + j0*16 + lm];
        float b1 = bias[512 + wc*128 + j1*16 + lm];
        #pragma unroll
        for (int r2 = 0; r2 < 4; r2++){
          int row = row0 + r2;
          float v0 = acc[ii][j0][r2] + b0;
          float v1 = acc[ii][j1][r2] + b1;
          float mx = fmaxf(v0, v1);
          #pragma unroll
          for (int msk = 8; msk; msk >>= 1) mx = fmaxf(mx, __shfl_xor(mx, msk));
          float e0 = expf(v0 - mx), e1 = expf(v1 - mx);
          float ss = e0 + e1;
          #pragma unroll
          for (int msk = 8; msk; msk >>= 1) ss += __shfl_xor(ss, msk);
          float inv = 1.f / ss;
          int b = row >> 13, n = row & 8191;
          float* op = swp + ((size_t)(b*8 + h)*8192 + n)*32;
          op[lm]      = e0 * inv;
          op[16 + lm] = e1 * inv;
        }
      }
    }
    return;
  }

  #pragma unroll
  for (int ii = 0; ii < 4; ii++){
    int row0 = m0 + wr*64 + ii*16 + lq*4;
    #pragma unroll
    for (int jj = 0; jj < NJ; jj++){
      int col = n0 + wc*(BN/2) + jj*16 + lm;
      float bv = bias[col];
      #pragma unroll
      for (int r2 = 0; r2 < 4; r2++){
        size_t idx = (size_t)(row0 + r2)*N + col;
        float v = acc[ii][jj][r2] + bv;
        if (EPI == 2) v += res[idx];
        if (EPI == 1)      ((__bf16*)outp)[idx] = (__bf16)gelu_f(v);
        else if (EPI == 4) ((__bf16*)outp)[idx] = (__bf16)v;     // fx_mid bf16
        else               ((float*)outp)[idx]  = v;
      }
    }
  }
}

// ---------------- LayerNorm (512 cols), fp32 in -> bf16 out; 1 wave/row ----------------
__global__ __launch_bounds__(256) void ln_k(const float* __restrict__ x, const float* __restrict__ g,
                                            const float* __restrict__ b, __bf16* __restrict__ out)
{
  int w = threadIdx.x >> 6, lane = threadIdx.x & 63;
  int row = blockIdx.x*4 + w;
  const float* xr = x + (size_t)row*512 + lane*8;
  float v[8];
  *(f32x4*)&v[0] = *(const f32x4*)xr;
  *(f32x4*)&v[4] = *(const f32x4*)(xr + 4);
  float s = 0.f, sq = 0.f;
  #pragma unroll
  for (int e = 0; e < 8; e++){ s += v[e]; sq += v[e]*v[e]; }
  #pragma unroll
  for (int off = 32; off; off >>= 1){ s += __shfl_xor(s, off); sq += __shfl_xor(sq, off); }
  float mean = s * (1.f/512.f);
  float var  = sq * (1.f/512.f) - mean*mean;
  float rstd = rsqrtf(var + 1e-5f);
  float gv[8], bv[8];
  *(f32x4*)&gv[0] = *(const f32x4*)(g + lane*8);
  *(f32x4*)&gv[4] = *(const f32x4*)(g + lane*8 + 4);
  *(f32x4*)&bv[0] = *(const f32x4*)(b + lane*8);
  *(f32x4*)&bv[4] = *(const f32x4*)(b + lane*8 + 4);
  __bf16* op = out + (size_t)row*512 + lane*8;
  #pragma unroll
  for (int e = 0; e < 8; e++) op[e] = (__bf16)((v[e]-mean)*rstd*gv[e] + bv[e]);
}

// ---------------- token partial: per (chunk, bh) accumulate sw^T @ fx_mid over 512 n (fx_mid bf16) ----------------
__global__ __launch_bounds__(256) void token_part_k(const __bf16* __restrict__ fxmid, const float* __restrict__ sw,
                                                    float* __restrict__ pt, float* __restrict__ ptm)
{
  __shared__ float fxl[32][64];
  __shared__ float swl[32][32];
  int t = threadIdx.x;
  int chunk = blockIdx.x, bh = blockIdx.y;
  int b = bh >> 3, h = bh & 7;
  int d = t & 63, gg = (t >> 6) * 8;
  float acc[8] = {0,0,0,0,0,0,0,0};
  float macc = 0.f;
  for (int s = 0; s < 16; s++){
    int nbase = chunk*512 + s*32;
    __syncthreads();
    #pragma unroll
    for (int i = 0; i < 2; i++){
      int e = t + 256*i; int rv = e >> 4, c4 = e & 15;
      bf16x4 v = *(const bf16x4*)&fxmid[((size_t)(b*8192 + nbase + rv))*512 + h*64 + c4*4];
      fxl[rv][c4*4+0] = (float)v[0];
      fxl[rv][c4*4+1] = (float)v[1];
      fxl[rv][c4*4+2] = (float)v[2];
      fxl[rv][c4*4+3] = (float)v[3];
    }
    { int rv = t >> 3, c4 = t & 7;
      *(f32x4*)&swl[rv][c4*4] = *(const f32x4*)&sw[((size_t)bh*8192 + nbase + rv)*32 + c4*4]; }
    __syncthreads();
    for (int nn = 0; nn < 32; nn++){
      float f = fxl[nn][d];
      #pragma unroll
      for (int jj = 0; jj < 8; jj++) acc[jj] += f * swl[nn][gg+jj];
    }
    if (t < 32){ for (int nn = 0; nn < 32; nn++) macc += swl[nn][t]; }
  }
  int cb = chunk*16 + bh;
  #pragma unroll
  for (int jj = 0; jj < 8; jj++)
    pt[((size_t)cb*32 + gg + jj)*64 + d] = acc[jj];
  if (t < 32) ptm[cb*32 + t] = macc;
}

// ---------------- token reduce + tiny attention per (b,h), fused ----------------
__global__ __launch_bounds__(256) void attn_k(const float* __restrict__ pt, const float* __restrict__ ptm,
                                              const float* __restrict__ Wq, const float* __restrict__ Wk,
                                              const float* __restrict__ Wv, float* __restrict__ ot)
{
  __shared__ float tok[32][64];
  __shared__ float ml[32];
  __shared__ float qq[32][65], kk2[32][65], vv[32][65];
  __shared__ float at[32][33];
  int t = threadIdx.x, bh = blockIdx.x;
  if (t < 32){
    float s = 0.f;
    for (int c = 0; c < 16; c++) s += ptm[(c*16 + bh)*32 + t];
    ml[t] = s + 1e-5f;
  }
  __syncthreads();
  #pragma unroll
  for (int i = 0; i < 8; i++){
    int e = t + 256*i; int g = e >> 6, d = e & 63;
    float s = 0.f;
    for (int c = 0; c < 16; c++) s += pt[((size_t)(c*16 + bh)*32 + g)*64 + d];
    tok[g][d] = s / ml[g];
  }
  __syncthreads();
  #pragma unroll
  for (int i = 0; i < 8; i++){
    int e = t + 256*i; int g = e >> 6, j = e & 63;
    float aq = 0.f, ak = 0.f, av = 0.f;
    for (int d = 0; d < 64; d++){
      float tv = tok[g][d];
      aq += tv * Wq[d*64 + j];
      ak += tv * Wk[d*64 + j];
      av += tv * Wv[d*64 + j];
    }
    qq[g][j] = aq; kk2[g][j] = ak; vv[g][j] = av;
  }
  __syncthreads();
  #pragma unroll
  for (int i = 0; i < 4; i++){
    int e = t + 256*i; int g = e >> 5, j2 = e & 31;
    float s2 = 0.f;
    for (int d = 0; d < 64; d++) s2 += qq[g][d] * kk2[j2][d];
    at[g][j2] = s2 * 0.125f;
  }
  __syncthreads();
  if (t < 32){
    float mx = at[t][0];
    for (int j = 1; j < 32; j++) mx = fmaxf(mx, at[t][j]);
    float ss = 0.f;
    for (int j = 0; j < 32; j++){ float e2 = expf(at[t][j]-mx); at[t][j] = e2; ss += e2; }
    float inv = 1.f / ss;
    for (int j = 0; j < 32; j++) at[t][j] *= inv;
  }
  __syncthreads();
  #pragma unroll
  for (int i = 0; i < 8; i++){
    int e = t + 256*i; int g = e >> 6, d = e & 63;
    float s3 = 0.f;
    for (int j = 0; j < 32; j++) s3 += at[g][j] * vv[j][d];
    ot[(size_t)bh*2048 + e] = s3;
  }
}

// ---------------- de-slice: 1 barrier, hoisted ot-frags, bf16x4 stores ----------------
__global__ __launch_bounds__(256) void deslice_k(const float* __restrict__ ot, const float* __restrict__ sw,
                                                 __bf16* __restrict__ outb)
{
  __shared__ float otl[32][64];
  __shared__ float swl[128][36];
  int t = threadIdx.x;
  int chunk = blockIdx.x, bh = blockIdx.y;
  int b = bh >> 3, h = bh & 7;
  int n0 = chunk*128;
  #pragma unroll
  for (int i = 0; i < 8; i++){
    int e = t + 256*i;
    otl[e>>6][e&63] = ot[(size_t)bh*2048 + e];
  }
  {
    int r = t >> 1, half = t & 1;
    const float* sp = sw + ((size_t)bh*8192 + n0 + r)*32 + half*16;
    float* dp = &swl[r][half*16];
    #pragma unroll
    for (int q = 0; q < 4; q++) *(f32x4*)(dp + q*4) = *(const f32x4*)(sp + q*4);
  }
  __syncthreads();
  const int nl = t >> 4;
  const int d0 = (t & 15) * 4;
  float o[8][4] = {};
  for (int g = 0; g < 32; g++){
    f32x4 ov = *(const f32x4*)&otl[g][d0];
    #pragma unroll
    for (int p = 0; p < 8; p++){
      float s = swl[p*16 + nl][g];
      o[p][0] += s * ov[0]; o[p][1] += s * ov[1];
      o[p][2] += s * ov[2]; o[p][3] += s * ov[3];
    }
  }
  #pragma unroll
  for (int p = 0; p < 8; p++){
    int n = n0 + p*16 + nl;
    bf16x4 v;
    v[0] = (__bf16)o[p][0]; v[1] = (__bf16)o[p][1];
    v[2] = (__bf16)o[p][2]; v[3] = (__bf16)o[p][3];
    *(bf16x4*)&outb[((size_t)(b*8192 + n))*512 + h*64 + d0] = v;
  }
}

// ---------------- final head ----------------
__global__ __launch_bounds__(256) void head_k(const float* __restrict__ x, const float* __restrict__ g,
                                              const float* __restrict__ b, const float* __restrict__ Wout,
                                              const float* __restrict__ bout, float* __restrict__ out)
{
  int w = threadIdx.x >> 6, lane = threadIdx.x & 63;
  int row = blockIdx.x*4 + w;
  const float* xr = x + (size_t)row*512 + lane*8;
  float v[8];
  *(f32x4*)&v[0] = *(const f32x4*)xr;
  *(f32x4*)&v[4] = *(const f32x4*)(xr + 4);
  float s = 0.f, sq = 0.f;
  #pragma unroll
  for (int e = 0; e < 8; e++){ s += v[e]; sq += v[e]*v[e]; }
  #pragma unroll
  for (int off = 32; off; off >>= 1){ s += __shfl_xor(s, off); sq += __shfl_xor(sq, off); }
  float mean = s * (1.f/512.f);
  float rstd = rsqrtf(sq * (1.f/512.f) - mean*mean + 1e-5f);
  float o[4] = {0,0,0,0};
  #pragma unroll
  for (int e = 0; e < 8; e++){
    int c = lane*8 + e;
    float yn = (v[e]-mean)*rstd*g[c] + b[c];
    const float* wr = Wout + (size_t)c*4;
    o[0] += yn*wr[0]; o[1] += yn*wr[1]; o[2] += yn*wr[2]; o[3] += yn*wr[3];
  }
  #pragma unroll
  for (int off = 32; off; off >>= 1){
    #pragma unroll
    for (int j = 0; j < 4; j++) o[j] += __shfl_xor(o[j], off);
  }
  if (lane == 0){
    #pragma unroll
    for (int j = 0; j < 4; j++) out[(size_t)row*4 + j] = o[j] + bout[j];
  }
}

extern "C" void kernel_launch(void* const* d_in, const int* in_sizes, int n_in,
                              void* d_out, int out_size, void* d_ws, size_t ws_size,
                              hipStream_t stream)
{
  const float* fun    = (const float*)d_in[0];
  const float* emb    = (const float*)d_in[1];
  const float* W_pre1 = (const float*)d_in[2];
  const float* b_pre1 = (const float*)d_in[3];
  const float* W_pre2 = (const float*)d_in[4];
  const float* b_pre2 = (const float*)d_in[5];
  const float* placeholder = (const float*)d_in[6];
  const float* ln1_g  = (const float*)d_in[7];
  const float* ln1_b  = (const float*)d_in[8];
  const float* Wfx    = (const float*)d_in[9];
  const float* bfx    = (const float*)d_in[10];
  const float* Wx     = (const float*)d_in[11];
  const float* bx     = (const float*)d_in[12];
  const float* Wslice = (const float*)d_in[13];
  const float* bslice = (const float*)d_in[14];
  const float* temp   = (const float*)d_in[15];
  const float* Wq     = (const float*)d_in[16];
  const float* Wk     = (const float*)d_in[17];
  const float* Wv     = (const float*)d_in[18];
  const float* Wo     = (const float*)d_in[19];
  const float* bo     = (const float*)d_in[20];
  const float* ln2_g  = (const float*)d_in[21];
  const float* ln2_b  = (const float*)d_in[22];
  const float* Wm1    = (const float*)d_in[23];
  const float* bm1    = (const float*)d_in[24];
  const float* Wm2    = (const float*)d_in[25];
  const float* bm2    = (const float*)d_in[26];
  const float* lnf_g  = (const float*)d_in[27];
  const float* lnf_b  = (const float*)d_in[28];
  const float* Wout   = (const float*)d_in[29];
  const float* bout   = (const float*)d_in[30];

  char* ws = (char*)d_ws;
  float*  fx     = (float*)(ws + OFF_FX);
  __bf16* hbf    = (__bf16*)(ws + OFF_H);
  __bf16* fxmid  = (__bf16*)(ws + OFF_FXMID);
  float*  sw     = (float*)(ws + OFF_SW);
  __bf16* mlph   = (__bf16*)(ws + OFF_MLPH);
  __bf16* h1bf   = (__bf16*)(ws + OFF_H1);
  __bf16* outb   = (__bf16*)(ws + OFF_OUTB);
  float*  pt     = (float*)(ws + OFF_PT);
  float*  ptm    = (float*)(ws + OFF_PTM);
  float*  ot     = (float*)(ws + OFF_OT);
  __bf16* Wpre2t = (__bf16*)(ws + OFF_WT);
  __bf16* Btcat  = (__bf16*)(ws + OFF_WT + 1048576);
  __bf16* Wot    = (__bf16*)(ws + OFF_WT + 4194304);
  __bf16* Wm1t   = (__bf16*)(ws + OFF_WT + 6291456);
  __bf16* Wm2t   = (__bf16*)(ws + OFF_WT + 14680064);
  float*  bcat   = (float*)(ws + OFF_BIAS);
  float*  bpre2p = (float*)(ws + OFF_BIAS + 4*768*4);

  // ---- weight prep ----
  wtrans_k<<<dim3(16,8,1), 256,0,stream>>>(W_pre2, Wpre2t, 1024, 512, 0, 0);
  wtrans_k<<<dim3(8,8,4),  256,0,stream>>>(Wfx, Btcat, 512, 512, 262144, 393216);  // rows 0-511 of each cat
  wtrans_k<<<dim3(8,8,4),  256,0,stream>>>(Wo,  Wot,  512, 512, 262144, 262144);
  wtrans_k<<<dim3(8,32,4), 256,0,stream>>>(Wm1, Wm1t, 512, 2048, 1048576, 1048576);
  wtrans_k<<<dim3(32,8,4), 256,0,stream>>>(Wm2, Wm2t, 2048, 512, 1048576, 1048576);
  prep_wxs_k<<<dim3(256,4),128,0,stream>>>(Wx, Wslice, bx, bslice, temp, Btcat, bcat);
  bias_setup_k<<<10,256,0,stream>>>(b_pre2, placeholder, bfx, bpre2p, bcat);

  // ---- preprocess ----
  preproc1_k<<<4096,256,0,stream>>>(fun, emb, W_pre1, b_pre1, h1bf);
  // M=16384, N=512, K=1024 -> 256x128 tiles, grid 64x4
  gemm_wide<0,128><<<dim3(64,4),512,0,stream>>>(h1bf, Wpre2t, bpre2p, nullptr, (void*)fx, nullptr, 512, 10);

  // ---- layers ----
  for (int l = 0; l < 4; l++){
    ln_k<<<4096,256,0,stream>>>(fx, ln1_g + l*512, ln1_b + l*512, hbf);
    // K=512 -> 256x256 tiles, grid 64x3; y<2 write fx_mid bf16 (stride 512), y==2 fused softmax -> sw
    gemm_wide<4,256><<<dim3(64,3),512,0,stream>>>(hbf, Btcat + (size_t)l*393216, bcat + l*768, nullptr, (void*)fxmid, (void*)sw, 512, 9);
    token_part_k<<<dim3(16,16),256,0,stream>>>(fxmid, sw, pt, ptm);
    attn_k<<<16,256,0,stream>>>(pt, ptm, Wq + l*4096, Wk + l*4096, Wv + l*4096, ot);
    deslice_k<<<dim3(64,16),256,0,stream>>>(ot, sw, outb);
    // N=512, K=512 -> 256x128 tiles, grid 64x4
    gemm_wide<2,128><<<dim3(64,4),512,0,stream>>>(outb, Wot + (size_t)l*262144, bo + l*512, fx, (void*)fx, nullptr, 512, 9);
    ln_k<<<4096,256,0,stream>>>(fx, ln2_g + l*512, ln2_b + l*512, hbf);
    // N=2048, K=512 -> 256x256 tiles, grid 64x8
    gemm_wide<1,256><<<dim3(64,8),512,0,stream>>>(hbf, Wm1t + (size_t)l*1048576, bm1 + l*2048, nullptr, (void*)mlph, nullptr, 2048, 9);
    // N=512, K=2048 -> 256x128 tiles, grid 64x4
    gemm_wide<2,128><<<dim3(64,4),512,0,stream>>>(mlph, Wm2t + (size_t)l*1048576, bm2 + l*512, fx, (void*)fx, nullptr, 512, 11);
  }

  // ---- head ----
  head_k<<<4096,256,0,stream>>>(fx, lnf_g, lnf_b, Wout, bout, (float*)d_out);
}

// Round 11
// 1282.078 us; speedup vs baseline: 1.5028x; 1.0406x over previous
//
#include <hip/hip_runtime.h>
#include <hip/hip_bf16.h>
#include <cstdint>
#include <cstddef>

typedef float  f32x4  __attribute__((ext_vector_type(4)));
typedef __bf16 bf16x8 __attribute__((ext_vector_type(8)));
typedef __bf16 bf16x4 __attribute__((ext_vector_type(4)));

#define DEV __device__ __forceinline__

DEV float gelu_f(float x){ return 0.5f * x * (1.0f + erff(x * 0.70710678118654752f)); }

// s_waitcnt imm (gfx9 enc): vmcnt[3:0]|[15:14], expcnt[6:4], lgkmcnt[11:8]
#define WAIT_LGKM0 0xC07F   // lgkmcnt(0), vm/exp no-wait

// fragment-major element offset for matrix with row-tile T=1<<lgT (256 for A / BN for B), K=1<<lgK.
// Layout: [tile][k_stage][subtile(16 rows)][lane=lq*16+lm][j] ; 1KB per (stage,subtile) chunk.
// Staging load for subtile f at stage kk is then CONTIGUOUS: base + f*512 + lane*8 elems.
DEV size_t fm_off(int m, int k, int lgT, int lgK){
  size_t tileblk = ((size_t)(((m >> lgT) << (lgK - 5)) | (k >> 5))) << (lgT + 5);
  int sub = (m >> 4) & ((1 << (lgT - 4)) - 1);
  return tileblk + ((size_t)sub << 9) + (size_t)(((((k >> 3) & 3) << 4) | (m & 15)) << 3) + (k & 7);
}

// ---------------- workspace layout (bytes) ----------------
static constexpr size_t OFF_FX     = 0;                       // fx fp32 [16384,512]     33554432
static constexpr size_t OFF_H      = 33554432;                // h bf16 [16384,512] frag-major
static constexpr size_t OFF_REGA   = 50331648;                // 67108864 region
static constexpr size_t OFF_FXMID  = OFF_REGA;                // bf16 [16384,512] row-major
static constexpr size_t OFF_SW     = OFF_REGA + 16777216;     // fp32 [16,8192,32]
static constexpr size_t OFF_MLPH   = OFF_REGA;                // bf16 [16384,2048] frag-major (after fxmid/sw dead)
static constexpr size_t OFF_H1     = OFF_REGA;                // bf16 [16384,1024] frag-major (preprocess only)
static constexpr size_t OFF_OUTB   = OFF_REGA + 67108864;     // bf16 [16384,512] frag-major
static constexpr size_t OFF_PT     = OFF_OUTB + 16777216;     // fp32 [16,16,32,64]
static constexpr size_t OFF_PTM    = OFF_PT + 2097152;        // fp32 [16,16,32]
static constexpr size_t OFF_OT     = OFF_PTM + 32768;         // fp32 [16,32,64]
static constexpr size_t OFF_WT     = OFF_OT + 131072;         // bf16 weights frag-major (22 MB)
static constexpr size_t OFF_BIAS   = OFF_WT + 23068672;       // bcat[4][768] f32, then bpre2p[512] f32

// ---------------- weight prep: W[K][N] fp32 -> frag-major bf16 Wt (as B operand, rows=N, cols=K) ----------------
__global__ __launch_bounds__(256) void wtrans_k(const float* __restrict__ W, __bf16* __restrict__ Wt,
                                                int K, int N, size_t wstride, size_t wtstride,
                                                int lgT, int lgK)
{
  __shared__ float tile[64][65];
  W  += (size_t)blockIdx.z * wstride;
  Wt += (size_t)blockIdx.z * wtstride;
  int t = threadIdx.x;
  int k0 = blockIdx.x * 64, n0 = blockIdx.y * 64;
  #pragma unroll
  for (int i = 0; i < 16; i++){
    int e = t + 256*i; int kk = e >> 6, nn = e & 63;
    tile[kk][nn] = W[(size_t)(k0+kk)*N + n0+nn];
  }
  __syncthreads();
  #pragma unroll
  for (int i2 = 0; i2 < 2; i2++){
    int c = t + 256*i2;                  // 0..511 : 64 rows x 8 k-chunks
    int nn = c >> 3, ck = (c & 7) * 8;
    bf16x8 v;
    #pragma unroll
    for (int j = 0; j < 8; j++) v[j] = (__bf16)tile[ck+j][nn];
    *(bf16x8*)&Wt[fm_off(n0+nn, k0+ck, lgT, lgK)] = v;
  }
}

// Wxs rows (n=512+hg of Btcat[l], frag-major lgT=8,lgK=9); blog -> bcat[l][512+hg]
__global__ __launch_bounds__(128) void prep_wxs_k(const float* __restrict__ Wx, const float* __restrict__ Wsl,
                                                  const float* __restrict__ bx, const float* __restrict__ bsl,
                                                  const float* __restrict__ temp,
                                                  __bf16* __restrict__ Btcat, float* __restrict__ bcat)
{
  __shared__ float wsc[64];
  __shared__ float wrow[512];
  int l = blockIdx.y;
  const float* Wx_l  = Wx  + (size_t)l*262144;
  const float* Wsl_l = Wsl + l*2048;
  const float* bx_l  = bx  + l*512;
  const float* bsl_l = bsl + l*32;
  __bf16* Bt_l = Btcat + (size_t)l*393216;
  float* blog_l = bcat + l*768 + 512;
  int hg = blockIdx.x; int h = hg >> 5, g = hg & 31;
  int t = threadIdx.x;
  if (t < 64) wsc[t] = Wsl_l[t*32 + g];
  __syncthreads();
  float invt = 1.0f / temp[l*8 + h];
  #pragma unroll
  for (int cc = 0; cc < 4; cc++){
    int c = t + cc*128;
    float a = 0.f;
    for (int d = 0; d < 64; d++) a += Wx_l[(size_t)c*512 + h*64 + d] * wsc[d];
    wrow[c] = a * invt;
  }
  if (t == 0){
    float a = 0.f;
    for (int d = 0; d < 64; d++) a += bx_l[h*64 + d] * wsc[d];
    blog_l[hg] = (a + bsl_l[g]) * invt;
  }
  __syncthreads();
  if (t < 64){
    int k0 = t*8;
    bf16x8 v;
    #pragma unroll
    for (int j = 0; j < 8; j++) v[j] = (__bf16)wrow[k0+j];
    *(bf16x8*)&Bt_l[fm_off(512 + hg, k0, 8, 9)] = v;
  }
}

__global__ __launch_bounds__(256) void bias_setup_k(const float* __restrict__ b_pre2, const float* __restrict__ placeholder,
                                                    const float* __restrict__ bfx,
                                                    float* __restrict__ bpre2p, float* __restrict__ bcat)
{
  int i = blockIdx.x*256 + threadIdx.x;   // 0..2559
  if (i < 512) bpre2p[i] = b_pre2[i] + placeholder[i];
  else if (i < 2560){
    int j = i - 512; int l = j >> 9, c = j & 511;
    bcat[l*768 + c] = bfx[l*512 + c];
  }
}

// ---------------- preprocess stage 1: h1 frag-major (lgT=8, lgK=10) ----------------
__global__ __launch_bounds__(256) void preproc1_k(const float* __restrict__ fun, const float* __restrict__ emb,
                                                  const float* __restrict__ W1, const float* __restrict__ b1,
                                                  __bf16* __restrict__ h1)
{
  __shared__ float w1l[10][1024];
  int t = threadIdx.x;
  for (int i = t*4; i < 10240; i += 1024) *(f32x4*)&w1l[0][i] = *(const f32x4*)&W1[i];
  __syncthreads();
  int rsel = t >> 7, c = t & 127, k0 = c*8;
  f32x4 bv0 = *(const f32x4*)&b1[k0];
  f32x4 bv1 = *(const f32x4*)&b1[k0+4];
  int r0 = blockIdx.x * 4;
  #pragma unroll
  for (int p = 0; p < 2; p++){
    int m = r0 + p*2 + rsel;
    const float* er = emb + (size_t)m*3;
    const float* fr = fun + (size_t)m*7;
    float x[10];
    x[0]=er[0]; x[1]=er[1]; x[2]=er[2];
    #pragma unroll
    for (int cc = 0; cc < 7; cc++) x[3+cc] = fr[cc];
    float a8[8];
    #pragma unroll
    for (int j = 0; j < 8; j++) a8[j] = (j < 4) ? bv0[j] : bv1[j-4];
    #pragma unroll
    for (int cc = 0; cc < 10; cc++){
      float xv = x[cc];
      #pragma unroll
      for (int j = 0; j < 8; j++) a8[j] += xv * w1l[cc][k0+j];
    }
    bf16x8 v;
    #pragma unroll
    for (int j = 0; j < 8; j++) v[j] = (__bf16)gelu_f(a8[j]);
    *(bf16x8*)&h1[fm_off(m, k0, 8, 10)] = v;
  }
}

// ---------------- wide-tile MFMA GEMM, frag-major A/B, reg-prefetch ping/pong ----------------
// R11: staging loads are now fully contiguous (one 16KB A block + one B block per stage,
// lane-linear) -- testing the segment-scatter delivery hypothesis.
// EPI: 0 = fp32 +bias | 1 = bf16 gelu -> frag-major (lgK=11) | 2 = fp32 +bias+res
//      4 = comb: y<2 -> bf16 +bias row-major (fx_mid N=512); y==2 -> fused slice-softmax -> sw
template<int EPI, int BN>
__global__ __launch_bounds__(512) void gemm_wide(const __bf16* __restrict__ A, const __bf16* __restrict__ Bt,
                                                 const float* __restrict__ bias, const float* __restrict__ res,
                                                 void* __restrict__ outp, void* __restrict__ outp2,
                                                 int N, int lgK)
{
  constexpr int NSUB_B = BN/16;
  constexpr int S = 16 + NSUB_B;           // 32 (BN=256) or 24 (BN=128)
  constexpr int Q = S/8;                   // subtiles staged per wave: 4 or 3
  constexpr int NJ = BN/32;                // n-frags per wave: 8 or 4
  constexpr int BADV = BN*32;              // B elems per stage
  __shared__ bf16x8 ldsAB[2][S][64];       // [buf][subtile][lane]
  const int tid = threadIdx.x;
  const int w = tid >> 6, lane = tid & 63;
  const int lm = lane & 15, lq = lane >> 4;
  const int wr = w >> 1, wc = w & 1;       // wave grid 4x2; wave tile 64 x (BN/2)
  const int m0 = blockIdx.x * 256, n0 = blockIdx.y * BN;
  const int niter = 1 << (lgK - 5);

  // contiguous staging pointers: A stage block = tile_m*(K/32)*8192 (+8192/stage);
  // B stage block = tile_n*(K/32)*BADV (+BADV/stage); chunk f at +f*512, lane at +lane*8.
  const __bf16* gp[Q];
  int adv[Q];
  #pragma unroll
  for (int q = 0; q < Q; q++){
    int f = w*Q + q;
    if (f < 16){
      gp[q] = A + (((size_t)blockIdx.x << (lgK - 5)) * 8192) + f*512 + lane*8;
      adv[q] = 8192;
    } else {
      gp[q] = Bt + (((size_t)blockIdx.y << (lgK - 5)) * BADV) + (f-16)*512 + lane*8;
      adv[q] = BADV;
    }
  }

  bf16x8 r[Q];
  #pragma unroll
  for (int q = 0; q < Q; q++){ r[q] = *(const bf16x8*)gp[q]; gp[q] += adv[q]; }

  f32x4 acc[4][NJ] = {};

  for (int i = 0; i < niter; ++i){
    __builtin_amdgcn_s_barrier();            // prev stage consumed (buf reuse safe)
    const unsigned buf = (unsigned)i & 1u;
    #pragma unroll
    for (int q = 0; q < Q; q++)              // ds_write_b128; compiler waits vmcnt for r[]
      ldsAB[buf][w*Q + q][lane] = r[q];
    if (i + 1 < niter){
      #pragma unroll
      for (int q = 0; q < Q; q++){ r[q] = *(const bf16x8*)gp[q]; gp[q] += adv[q]; }
    }
    __builtin_amdgcn_s_waitcnt(WAIT_LGKM0);  // own ds_writes visible
    __builtin_amdgcn_s_barrier();            // everyone's writes visible
    bf16x8 af[4], bfr[NJ];
    #pragma unroll
    for (int ii = 0; ii < 4; ii++)  af[ii]  = ldsAB[buf][wr*4 + ii][lane];
    #pragma unroll
    for (int jj = 0; jj < NJ; jj++) bfr[jj] = ldsAB[buf][16 + wc*NJ + jj][lane];
    #pragma unroll
    for (int ii = 0; ii < 4; ii++)
      #pragma unroll
      for (int jj = 0; jj < NJ; jj++)
        acc[ii][jj] = __builtin_amdgcn_mfma_f32_16x16x32_bf16(af[ii], bfr[jj], acc[ii][jj], 0, 0, 0);
  }

  if (EPI == 4 && blockIdx.y == 2){
    // fused slice-softmax: 32 logits of one (row,head) live in 2 jj-frags x 16 lm lanes.
    float* swp = (float*)outp2;
    #pragma unroll
    for (int ii = 0; ii < 4; ii++){
      int row0 = m0 + wr*64 + ii*16 + lq*4;
      #pragma unroll
      for (int hp = 0; hp < 4; hp++){
        int j0 = hp*2, j1 = j0 + 1;
        int h = wc*4 + hp;
        float b0 = bias[512 + wc*128 + j0*16 + lm];
        float b1 = bias[512 + wc*128 + j1*16 + lm];
        #pragma unroll
        for (int r2 = 0; r2 < 4; r2++){
          int row = row0 + r2;
          float v0 = acc[ii][j0][r2] + b0;
          float v1 = acc[ii][j1][r2] + b1;
          float mx = fmaxf(v0, v1);
          #pragma unroll
          for (int msk = 8; msk; msk >>= 1) mx = fmaxf(mx, __shfl_xor(mx, msk));
          float e0 = expf(v0 - mx), e1 = expf(v1 - mx);
          float ss = e0 + e1;
          #pragma unroll
          for (int msk = 8; msk; msk >>= 1) ss += __shfl_xor(ss, msk);
          float inv = 1.f / ss;
          int b = row >> 13, n = row & 8191;
          float* op = swp + ((size_t)(b*8 + h)*8192 + n)*32;
          op[lm]      = e0 * inv;
          op[16 + lm] = e1 * inv;
        }
      }
    }
    return;
  }

  #pragma unroll
  for (int ii = 0; ii < 4; ii++){
    int row0 = m0 + wr*64 + ii*16 + lq*4;
    #pragma unroll
    for (int jj = 0; jj < NJ; jj++){
      int col = n0 + wc*(BN/2) + jj*16 + lm;
      float bv = bias[col];
      #pragma unroll
      for (int r2 = 0; r2 < 4; r2++){
        int row = row0 + r2;
        float v = acc[ii][jj][r2] + bv;
        if (EPI == 1){
          ((__bf16*)outp)[fm_off(row, col, 8, 11)] = (__bf16)gelu_f(v);  // mlph frag-major (K_next=2048)
        } else {
          size_t idx = (size_t)row*N + col;
          if (EPI == 2) v += res[idx];
          if (EPI == 4) ((__bf16*)outp)[idx] = (__bf16)v;                // fx_mid bf16 row-major
          else          ((float*)outp)[idx]  = v;
        }
      }
    }
  }
}

// ---------------- LayerNorm (512 cols), fp32 in -> bf16 frag-major out (lgT=8,lgK=9); 1 wave/row ----------------
__global__ __launch_bounds__(256) void ln_k(const float* __restrict__ x, const float* __restrict__ g,
                                            const float* __restrict__ b, __bf16* __restrict__ out)
{
  int w = threadIdx.x >> 6, lane = threadIdx.x & 63;
  int row = blockIdx.x*4 + w;
  const float* xr = x + (size_t)row*512 + lane*8;
  float v[8];
  *(f32x4*)&v[0] = *(const f32x4*)xr;
  *(f32x4*)&v[4] = *(const f32x4*)(xr + 4);
  float s = 0.f, sq = 0.f;
  #pragma unroll
  for (int e = 0; e < 8; e++){ s += v[e]; sq += v[e]*v[e]; }
  #pragma unroll
  for (int off = 32; off; off >>= 1){ s += __shfl_xor(s, off); sq += __shfl_xor(sq, off); }
  float mean = s * (1.f/512.f);
  float var  = sq * (1.f/512.f) - mean*mean;
  float rstd = rsqrtf(var + 1e-5f);
  float gv[8], bv[8];
  *(f32x4*)&gv[0] = *(const f32x4*)(g + lane*8);
  *(f32x4*)&gv[4] = *(const f32x4*)(g + lane*8 + 4);
  *(f32x4*)&bv[0] = *(const f32x4*)(b + lane*8);
  *(f32x4*)&bv[4] = *(const f32x4*)(b + lane*8 + 4);
  bf16x8 o8;
  #pragma unroll
  for (int e = 0; e < 8; e++) o8[e] = (__bf16)((v[e]-mean)*rstd*gv[e] + bv[e]);
  *(bf16x8*)&out[fm_off(row, lane*8, 8, 9)] = o8;
}

// ---------------- token partial (fx_mid bf16 row-major) ----------------
__global__ __launch_bounds__(256) void token_part_k(const __bf16* __restrict__ fxmid, const float* __restrict__ sw,
                                                    float* __restrict__ pt, float* __restrict__ ptm)
{
  __shared__ float fxl[32][64];
  __shared__ float swl[32][32];
  int t = threadIdx.x;
  int chunk = blockIdx.x, bh = blockIdx.y;
  int b = bh >> 3, h = bh & 7;
  int d = t & 63, gg = (t >> 6) * 8;
  float acc[8] = {0,0,0,0,0,0,0,0};
  float macc = 0.f;
  for (int s = 0; s < 16; s++){
    int nbase = chunk*512 + s*32;
    __syncthreads();
    #pragma unroll
    for (int i = 0; i < 2; i++){
      int e = t + 256*i; int rv = e >> 4, c4 = e & 15;
      bf16x4 v = *(const bf16x4*)&fxmid[((size_t)(b*8192 + nbase + rv))*512 + h*64 + c4*4];
      fxl[rv][c4*4+0] = (float)v[0];
      fxl[rv][c4*4+1] = (float)v[1];
      fxl[rv][c4*4+2] = (float)v[2];
      fxl[rv][c4*4+3] = (float)v[3];
    }
    { int rv = t >> 3, c4 = t & 7;
      *(f32x4*)&swl[rv][c4*4] = *(const f32x4*)&sw[((size_t)bh*8192 + nbase + rv)*32 + c4*4]; }
    __syncthreads();
    for (int nn = 0; nn < 32; nn++){
      float f = fxl[nn][d];
      #pragma unroll
      for (int jj = 0; jj < 8; jj++) acc[jj] += f * swl[nn][gg+jj];
    }
    if (t < 32){ for (int nn = 0; nn < 32; nn++) macc += swl[nn][t]; }
  }
  int cb = chunk*16 + bh;
  #pragma unroll
  for (int jj = 0; jj < 8; jj++)
    pt[((size_t)cb*32 + gg + jj)*64 + d] = acc[jj];
  if (t < 32) ptm[cb*32 + t] = macc;
}

// ---------------- token reduce + tiny attention per (b,h), fused ----------------
__global__ __launch_bounds__(256) void attn_k(const float* __restrict__ pt, const float* __restrict__ ptm,
                                              const float* __restrict__ Wq, const float* __restrict__ Wk,
                                              const float* __restrict__ Wv, float* __restrict__ ot)
{
  __shared__ float tok[32][64];
  __shared__ float ml[32];
  __shared__ float qq[32][65], kk2[32][65], vv[32][65];
  __shared__ float at[32][33];
  int t = threadIdx.x, bh = blockIdx.x;
  if (t < 32){
    float s = 0.f;
    for (int c = 0; c < 16; c++) s += ptm[(c*16 + bh)*32 + t];
    ml[t] = s + 1e-5f;
  }
  __syncthreads();
  #pragma unroll
  for (int i = 0; i < 8; i++){
    int e = t + 256*i; int g = e >> 6, d = e & 63;
    float s = 0.f;
    for (int c = 0; c < 16; c++) s += pt[((size_t)(c*16 + bh)*32 + g)*64 + d];
    tok[g][d] = s / ml[g];
  }
  __syncthreads();
  #pragma unroll
  for (int i = 0; i < 8; i++){
    int e = t + 256*i; int g = e >> 6, j = e & 63;
    float aq = 0.f, ak = 0.f, av = 0.f;
    for (int d = 0; d < 64; d++){
      float tv = tok[g][d];
      aq += tv * Wq[d*64 + j];
      ak += tv * Wk[d*64 + j];
      av += tv * Wv[d*64 + j];
    }
    qq[g][j] = aq; kk2[g][j] = ak; vv[g][j] = av;
  }
  __syncthreads();
  #pragma unroll
  for (int i = 0; i < 4; i++){
    int e = t + 256*i; int g = e >> 5, j2 = e & 31;
    float s2 = 0.f;
    for (int d = 0; d < 64; d++) s2 += qq[g][d] * kk2[j2][d];
    at[g][j2] = s2 * 0.125f;
  }
  __syncthreads();
  if (t < 32){
    float mx = at[t][0];
    for (int j = 1; j < 32; j++) mx = fmaxf(mx, at[t][j]);
    float ss = 0.f;
    for (int j = 0; j < 32; j++){ float e2 = expf(at[t][j]-mx); at[t][j] = e2; ss += e2; }
    float inv = 1.f / ss;
    for (int j = 0; j < 32; j++) at[t][j] *= inv;
  }
  __syncthreads();
  #pragma unroll
  for (int i = 0; i < 8; i++){
    int e = t + 256*i; int g = e >> 6, d = e & 63;
    float s3 = 0.f;
    for (int j = 0; j < 32; j++) s3 += at[g][j] * vv[j][d];
    ot[(size_t)bh*2048 + e] = s3;
  }
}

// ---------------- de-slice: outb frag-major (lgT=8,lgK=9); bf16x8 chunk stores ----------------
__global__ __launch_bounds__(256) void deslice_k(const float* __restrict__ ot, const float* __restrict__ sw,
                                                 __bf16* __restrict__ outb)
{
  __shared__ float otl[32][64];
  __shared__ float swl[128][36];
  int t = threadIdx.x;
  int chunk = blockIdx.x, bh = blockIdx.y;
  int b = bh >> 3, h = bh & 7;
  int n0 = chunk*128;
  #pragma unroll
  for (int i = 0; i < 8; i++){
    int e = t + 256*i;
    otl[e>>6][e&63] = ot[(size_t)bh*2048 + e];
  }
  {
    int r = t >> 1, half = t & 1;
    const float* sp = sw + ((size_t)bh*8192 + n0 + r)*32 + half*16;
    float* dp = &swl[r][half*16];
    #pragma unroll
    for (int q = 0; q < 4; q++) *(f32x4*)(dp + q*4) = *(const f32x4*)(sp + q*4);
  }
  __syncthreads();
  const int slot = t >> 3;                 // 0..31 row slot
  const int d0 = (t & 7) * 8;              // 0..56
  float o[4][8] = {};
  for (int g = 0; g < 32; g++){
    f32x4 ov0 = *(const f32x4*)&otl[g][d0];
    f32x4 ov1 = *(const f32x4*)&otl[g][d0+4];
    #pragma unroll
    for (int p = 0; p < 4; p++){
      float s = swl[p*32 + slot][g];
      o[p][0] += s*ov0[0]; o[p][1] += s*ov0[1]; o[p][2] += s*ov0[2]; o[p][3] += s*ov0[3];
      o[p][4] += s*ov1[0]; o[p][5] += s*ov1[1]; o[p][6] += s*ov1[2]; o[p][7] += s*ov1[3];
    }
  }
  #pragma unroll
  for (int p = 0; p < 4; p++){
    int n = n0 + p*32 + slot;
    int m = b*8192 + n;
    int k = h*64 + d0;
    bf16x8 v;
    #pragma unroll
    for (int j = 0; j < 8; j++) v[j] = (__bf16)o[p][j];
    *(bf16x8*)&outb[fm_off(m, k, 8, 9)] = v;
  }
}

// ---------------- final head ----------------
__global__ __launch_bounds__(256) void head_k(const float* __restrict__ x, const float* __restrict__ g,
                                              const float* __restrict__ b, const float* __restrict__ Wout,
                                              const float* __restrict__ bout, float* __restrict__ out)
{
  int w = threadIdx.x >> 6, lane = threadIdx.x & 63;
  int row = blockIdx.x*4 + w;
  const float* xr = x + (size_t)row*512 + lane*8;
  float v[8];
  *(f32x4*)&v[0] = *(const f32x4*)xr;
  *(f32x4*)&v[4] = *(const f32x4*)(xr + 4);
  float s = 0.f, sq = 0.f;
  #pragma unroll
  for (int e = 0; e < 8; e++){ s += v[e]; sq += v[e]*v[e]; }
  #pragma unroll
  for (int off = 32; off; off >>= 1){ s += __shfl_xor(s, off); sq += __shfl_xor(sq, off); }
  float mean = s * (1.f/512.f);
  float rstd = rsqrtf(sq * (1.f/512.f) - mean*mean + 1e-5f);
  float o[4] = {0,0,0,0};
  #pragma unroll
  for (int e = 0; e < 8; e++){
    int c = lane*8 + e;
    float yn = (v[e]-mean)*rstd*g[c] + b[c];
    const float* wr = Wout + (size_t)c*4;
    o[0] += yn*wr[0]; o[1] += yn*wr[1]; o[2] += yn*wr[2]; o[3] += yn*wr[3];
  }
  #pragma unroll
  for (int off = 32; off; off >>= 1){
    #pragma unroll
    for (int j = 0; j < 4; j++) o[j] += __shfl_xor(o[j], off);
  }
  if (lane == 0){
    #pragma unroll
    for (int j = 0; j < 4; j++) out[(size_t)row*4 + j] = o[j] + bout[j];
  }
}

extern "C" void kernel_launch(void* const* d_in, const int* in_sizes, int n_in,
                              void* d_out, int out_size, void* d_ws, size_t ws_size,
                              hipStream_t stream)
{
  const float* fun    = (const float*)d_in[0];
  const float* emb    = (const float*)d_in[1];
  const float* W_pre1 = (const float*)d_in[2];
  const float* b_pre1 = (const float*)d_in[3];
  const float* W_pre2 = (const float*)d_in[4];
  const float* b_pre2 = (const float*)d_in[5];
  const float* placeholder = (const float*)d_in[6];
  const float* ln1_g  = (const float*)d_in[7];
  const float* ln1_b  = (const float*)d_in[8];
  const float* Wfx    = (const float*)d_in[9];
  const float* bfx    = (const float*)d_in[10];
  const float* Wx     = (const float*)d_in[11];
  const float* bx     = (const float*)d_in[12];
  const float* Wslice = (const float*)d_in[13];
  const float* bslice = (const float*)d_in[14];
  const float* temp   = (const float*)d_in[15];
  const float* Wq     = (const float*)d_in[16];
  const float* Wk     = (const float*)d_in[17];
  const float* Wv     = (const float*)d_in[18];
  const float* Wo     = (const float*)d_in[19];
  const float* bo     = (const float*)d_in[20];
  const float* ln2_g  = (const float*)d_in[21];
  const float* ln2_b  = (const float*)d_in[22];
  const float* Wm1    = (const float*)d_in[23];
  const float* bm1    = (const float*)d_in[24];
  const float* Wm2    = (const float*)d_in[25];
  const float* bm2    = (const float*)d_in[26];
  const float* lnf_g  = (const float*)d_in[27];
  const float* lnf_b  = (const float*)d_in[28];
  const float* Wout   = (const float*)d_in[29];
  const float* bout   = (const float*)d_in[30];

  char* ws = (char*)d_ws;
  float*  fx     = (float*)(ws + OFF_FX);
  __bf16* hbf    = (__bf16*)(ws + OFF_H);
  __bf16* fxmid  = (__bf16*)(ws + OFF_FXMID);
  float*  sw     = (float*)(ws + OFF_SW);
  __bf16* mlph   = (__bf16*)(ws + OFF_MLPH);
  __bf16* h1bf   = (__bf16*)(ws + OFF_H1);
  __bf16* outb   = (__bf16*)(ws + OFF_OUTB);
  float*  pt     = (float*)(ws + OFF_PT);
  float*  ptm    = (float*)(ws + OFF_PTM);
  float*  ot     = (float*)(ws + OFF_OT);
  __bf16* Wpre2t = (__bf16*)(ws + OFF_WT);
  __bf16* Btcat  = (__bf16*)(ws + OFF_WT + 1048576);
  __bf16* Wot    = (__bf16*)(ws + OFF_WT + 4194304);
  __bf16* Wm1t   = (__bf16*)(ws + OFF_WT + 6291456);
  __bf16* Wm2t   = (__bf16*)(ws + OFF_WT + 14680064);
  float*  bcat   = (float*)(ws + OFF_BIAS);
  float*  bpre2p = (float*)(ws + OFF_BIAS + 4*768*4);

  // ---- weight prep (frag-major per consumer GEMM's BN and K) ----
  wtrans_k<<<dim3(16,8,1), 256,0,stream>>>(W_pre2, Wpre2t, 1024, 512, 0, 0, 7, 10);       // BN=128, K=1024
  wtrans_k<<<dim3(8,8,4),  256,0,stream>>>(Wfx, Btcat, 512, 512, 262144, 393216, 8, 9);   // BN=256, K=512 (tiles 0-1)
  wtrans_k<<<dim3(8,8,4),  256,0,stream>>>(Wo,  Wot,  512, 512, 262144, 262144, 7, 9);    // BN=128, K=512
  wtrans_k<<<dim3(8,32,4), 256,0,stream>>>(Wm1, Wm1t, 512, 2048, 1048576, 1048576, 8, 9); // BN=256, K=512
  wtrans_k<<<dim3(32,8,4), 256,0,stream>>>(Wm2, Wm2t, 2048, 512, 1048576, 1048576, 7, 11);// BN=128, K=2048
  prep_wxs_k<<<dim3(256,4),128,0,stream>>>(Wx, Wslice, bx, bslice, temp, Btcat, bcat);
  bias_setup_k<<<10,256,0,stream>>>(b_pre2, placeholder, bfx, bpre2p, bcat);

  // ---- preprocess ----
  preproc1_k<<<4096,256,0,stream>>>(fun, emb, W_pre1, b_pre1, h1bf);
  // M=16384, N=512, K=1024 -> 256x128 tiles, grid 64x4
  gemm_wide<0,128><<<dim3(64,4),512,0,stream>>>(h1bf, Wpre2t, bpre2p, nullptr, (void*)fx, nullptr, 512, 10);

  // ---- layers ----
  for (int l = 0; l < 4; l++){
    ln_k<<<4096,256,0,stream>>>(fx, ln1_g + l*512, ln1_b + l*512, hbf);
    // K=512 -> 256x256 tiles, grid 64x3; y<2 write fx_mid bf16 row-major, y==2 fused softmax -> sw
    gemm_wide<4,256><<<dim3(64,3),512,0,stream>>>(hbf, Btcat + (size_t)l*393216, bcat + l*768, nullptr, (void*)fxmid, (void*)sw, 512, 9);
    token_part_k<<<dim3(16,16),256,0,stream>>>(fxmid, sw, pt, ptm);
    attn_k<<<16,256,0,stream>>>(pt, ptm, Wq + l*4096, Wk + l*4096, Wv + l*4096, ot);
    deslice_k<<<dim3(64,16),256,0,stream>>>(ot, sw, outb);
    // N=512, K=512 -> 256x128 tiles, grid 64x4
    gemm_wide<2,128><<<dim3(64,4),512,0,stream>>>(outb, Wot + (size_t)l*262144, bo + l*512, fx, (void*)fx, nullptr, 512, 9);
    ln_k<<<4096,256,0,stream>>>(fx, ln2_g + l*512, ln2_b + l*512, hbf);
    // N=2048, K=512 -> 256x256 tiles, grid 64x8; mlph written frag-major (K_next=2048)
    gemm_wide<1,256><<<dim3(64,8),512,0,stream>>>(hbf, Wm1t + (size_t)l*1048576, bm1 + l*2048, nullptr, (void*)mlph, nullptr, 2048, 9);
    // N=512, K=2048 -> 256x128 tiles, grid 64x4
    gemm_wide<2,128><<<dim3(64,4),512,0,stream>>>(mlph, Wm2t + (size_t)l*1048576, bm2 + l*512, fx, (void*)fx, nullptr, 512, 11);
  }

  // ---- head ----
  head_k<<<4096,256,0,stream>>>(fx, lnf_g, lnf_b, Wout, bout, (float*)d_out);
}